// Round 19
// baseline (819.689 us; speedup 1.0000x reference)
//
#include <hip/hip_runtime.h>
#include <stdint.h>

#define NB 2
#define NS 2048
#define ND 2048
#define NH 16
#define NHD 128
#define NFF 8192
#define NBS (NB*NS)   // 4096 rows
#define NQKV 2304     // 2048 q + 256 kv

typedef unsigned short u16;
typedef __attribute__((ext_vector_type(8))) short bf16x8;   // 8 bf16 = 4 VGPRs
typedef __attribute__((ext_vector_type(4))) unsigned short u16x4;
typedef __attribute__((ext_vector_type(4))) float f32x4;

__device__ __forceinline__ u16 f2bf(float f) {
  union { float f; unsigned u; } v; v.f = f;
  unsigned r = v.u + 0x7fffu + ((v.u >> 16) & 1u);   // RNE
  return (u16)(r >> 16);
}
__device__ __forceinline__ float bf2f(u16 h) {
  union { unsigned u; float f; } v; v.u = ((unsigned)h) << 16;
  return v.f;
}
__device__ __forceinline__ void async_cp16(const void* g, void* l) {
  __builtin_amdgcn_global_load_lds((const __attribute__((address_space(1))) void*)g,
                                   (__attribute__((address_space(3))) void*)l, 16, 0, 0);
}
__device__ __forceinline__ void barrier_nofence() {
  asm volatile("" ::: "memory");
  __builtin_amdgcn_s_barrier();
  asm volatile("" ::: "memory");
}

// ---------------- fp32 -> bf16 ----------------
__global__ void cvt_bf16_kernel(const float* __restrict__ in, u16* __restrict__ out, int n4) {
  int i = blockIdx.x * blockDim.x + threadIdx.x;
  if (i >= n4) return;
  float4 v = reinterpret_cast<const float4*>(in)[i];
  u16x4 o; o.x = f2bf(v.x); o.y = f2bf(v.y); o.z = f2bf(v.z); o.w = f2bf(v.w);
  reinterpret_cast<u16x4*>(out)[i] = o;
}

// ---------------- RMSNorm, one block per row. BF16IN: 0=fp32 input, 1=bf16 input ----------------
template <int BF16IN>
__global__ __launch_bounds__(256) void rmsnorm_kernel(const void* __restrict__ xin,
                                                      const float* __restrict__ w,
                                                      u16* __restrict__ out) {
  const int row = blockIdx.x, tid = threadIdx.x;
  float vs[8];
  if constexpr (BF16IN == 0) {
    const float* xr = (const float*)xin + (size_t)row * ND;
    float4 a = *reinterpret_cast<const float4*>(xr + tid * 8);
    float4 b = *reinterpret_cast<const float4*>(xr + tid * 8 + 4);
    vs[0]=a.x; vs[1]=a.y; vs[2]=a.z; vs[3]=a.w; vs[4]=b.x; vs[5]=b.y; vs[6]=b.z; vs[7]=b.w;
  } else {
    const u16* xr = (const u16*)xin + (size_t)row * ND;
    bf16x8 v = *reinterpret_cast<const bf16x8*>(xr + tid * 8);
#pragma unroll
    for (int j = 0; j < 8; ++j) vs[j] = bf2f((u16)v[j]);
  }
  float ss = 0.f;
#pragma unroll
  for (int j = 0; j < 8; ++j) ss += vs[j] * vs[j];
#pragma unroll
  for (int off = 32; off > 0; off >>= 1) ss += __shfl_down(ss, off);
  __shared__ float red[4];
  __shared__ float rinv_s;
  if ((tid & 63) == 0) red[tid >> 6] = ss;
  __syncthreads();
  if (tid == 0) rinv_s = rsqrtf((red[0] + red[1] + red[2] + red[3]) * (1.0f / ND) + 1e-6f);
  __syncthreads();
  const float rinv = rinv_s;
  const float* wr = w + tid * 8;
  u16* orow = out + (size_t)row * ND + tid * 8;
#pragma unroll
  for (int j = 0; j < 8; ++j) orow[j] = f2bf(vs[j] * rinv * wr[j]);
}

// ---------------- RoPE cos/sin table [S][64] ----------------
__global__ void rope_table_kernel(float* __restrict__ cosT, float* __restrict__ sinT) {
  int i = blockIdx.x * blockDim.x + threadIdx.x;
  if (i >= NS * 64) return;
  int s = i >> 6, d = i & 63;
  float freq = expf(-(float)d * (9.210340371976184f / 64.0f));  // 10000^(-d/64)
  float ang = (float)s * freq;
  cosT[i] = cosf(ang);
  sinT[i] = sinf(ang);
}

// ---- RoPE for Q: qkvraw [B,S,2304] bf16 -> [B*H, S, HD] bf16, pre-scaled 1/sqrt(HD) ----
__global__ void rope_q_kernel(const u16* __restrict__ qkvraw, const float* __restrict__ cosT,
                              const float* __restrict__ sinT, u16* __restrict__ qout) {
  int i = blockIdx.x * blockDim.x + threadIdx.x;
  if (i >= NB * NS * NH * 64) return;
  int d = i & 63, h = (i >> 6) & 15, s = (i >> 10) & (NS - 1), b = i >> 21;
  size_t rrow = ((size_t)(b * NS + s)) * NQKV + h * NHD;
  float t1 = bf2f(qkvraw[rrow + d]);
  float t2 = bf2f(qkvraw[rrow + d + 64]);
  float c = cosT[(s << 6) + d], sn = sinT[(s << 6) + d];
  const float scale = 0.08838834764831845f;  // 1/sqrt(128)
  size_t orow = (((size_t)(b * NH + h)) * NS + s) * NHD;
  qout[orow + d]      = f2bf((t1 * c - t2 * sn) * scale);
  qout[orow + d + 64] = f2bf((t2 * c + t1 * sn) * scale);
}

// ---- RoPE for K + transpose-copy V: qkvraw[...,2048+] -> k [B,S,HD], vt [B,128,S] ----
__global__ void rope_kv_kernel(const u16* __restrict__ qkvraw, const float* __restrict__ cosT,
                               const float* __restrict__ sinT, u16* __restrict__ kout,
                               u16* __restrict__ vtout) {
  int i = blockIdx.x * blockDim.x + threadIdx.x;
  if (i >= NB * NS * 64) return;
  int d = i & 63, s = (i >> 6) & (NS - 1), b = i >> 17;
  size_t rrow = ((size_t)(b * NS + s)) * NQKV + ND;
  float t1 = bf2f(qkvraw[rrow + d]);
  float t2 = bf2f(qkvraw[rrow + d + 64]);
  float c = cosT[(s << 6) + d], sn = sinT[(s << 6) + d];
  size_t orow = ((size_t)(b * NS + s)) * NHD;
  kout[orow + d]      = f2bf(t1 * c - t2 * sn);
  kout[orow + d + 64] = f2bf(t2 * c + t1 * sn);
  vtout[((size_t)(b * 128 + d)) * NS + s]      = qkvraw[rrow + 128 + d];
  vtout[((size_t)(b * 128 + d + 64)) * NS + s] = qkvraw[rrow + 128 + d + 64];
}

// ---------------- GEMM v9 (m97-structure + swizzle): C = A[M,K] @ W[N,K]^T (bf16) ----------------
// EPI: 0 = bf16 store; 2 = bf16 store silu(Aux_bf16)*acc (in-place ok);
//      3 = bf16 store of (acc + fp32 Aux); 4 = fp32 store of (acc + bf16 Aux)
template <int EPI>
__global__ __launch_bounds__(256) void gemm3_kernel(const u16* __restrict__ A,
                                                    const u16* __restrict__ W,
                                                    void* Out, const void* Aux,
                                                    int M, int N, int K) {
  __shared__ __align__(16) char As[128 * 128];
  __shared__ __align__(16) char Bs[128 * 128];
  const int tid = threadIdx.x, wave = tid >> 6, lane = tid & 63;
  const int lm = lane & 15, lg = lane >> 4;

  int bx, by;
  {
    const int gx = gridDim.x;
    if ((gx & 7) == 0) {
      const int id = blockIdx.y * gx + blockIdx.x;
      const int xcd = id & 7, rank = id >> 3;
      const int cw = gx >> 3;
      bx = xcd * cw + rank % cw;
      by = rank / cw;
    } else { bx = blockIdx.x; by = blockIdx.y; }
  }
  const int m0 = by * 128, n0 = bx * 128;
  const int wr = wave >> 1, wc = wave & 1;

  f32x4 acc[4][4];
#pragma unroll
  for (int i = 0; i < 4; ++i)
#pragma unroll
    for (int j = 0; j < 4; ++j) acc[i][j] = (f32x4){0.f, 0.f, 0.f, 0.f};

  for (int k0 = 0; k0 < K; k0 += 64) {
#pragma unroll
    for (int p = 0; p < 4; ++p) {
      int X = p * 4096 + tid * 16;
      int r = X >> 7;
      int sw = ((X >> 4) ^ (X >> 7)) & 7;
      async_cp16(A + (size_t)(m0 + r) * K + k0 + sw * 8, As + p * 4096 + wave * 1024);
      async_cp16(W + (size_t)(n0 + r) * K + k0 + sw * 8, Bs + p * 4096 + wave * 1024);
    }
    __syncthreads();
#pragma unroll
    for (int ks = 0; ks < 2; ++ks) {
      bf16x8 a[4], b[4];
#pragma unroll
      for (int i = 0; i < 4; ++i) {
        const int ra = wr * 64 + i * 16 + lm;
        const int sa = (ks * 4 + lg) ^ (ra & 7);
        a[i] = *(const bf16x8*)(As + ra * 128 + sa * 16);
        const int rb = wc * 64 + i * 16 + lm;
        const int sb = (ks * 4 + lg) ^ (rb & 7);
        b[i] = *(const bf16x8*)(Bs + rb * 128 + sb * 16);
      }
#pragma unroll
      for (int i = 0; i < 4; ++i)
#pragma unroll
        for (int j = 0; j < 4; ++j)
          acc[i][j] = __builtin_amdgcn_mfma_f32_16x16x32_bf16(a[i], b[j], acc[i][j], 0, 0, 0);
    }
    __syncthreads();
  }

#pragma unroll
  for (int i = 0; i < 4; ++i) {
    const int row_b = m0 + wr * 64 + i * 16 + lg * 4;
#pragma unroll
    for (int j = 0; j < 4; ++j) {
      const int col = n0 + wc * 64 + j * 16 + lm;
#pragma unroll
      for (int r = 0; r < 4; ++r) {
        size_t idx = (size_t)(row_b + r) * N + col;
        float v = acc[i][j][r];
        if constexpr (EPI == 0) {
          ((u16*)Out)[idx] = f2bf(v);
        } else if constexpr (EPI == 2) {
          float a1 = bf2f(((const u16*)Aux)[idx]);
          float s = a1 / (1.0f + expf(-a1));   // silu
          ((u16*)Out)[idx] = f2bf(s * v);
        } else if constexpr (EPI == 3) {
          ((u16*)Out)[idx] = f2bf(v + ((const float*)Aux)[idx]);
        } else {
          ((float*)Out)[idx] = v + bf2f(((const u16*)Aux)[idx]);
        }
      }
    }
  }
}

// ---------------- GEMM 8-phase (K-split halves, counted vmcnt): C = A @ W^T bf16 ----------------
// Tile 256 x BN (BN in {256,128}), BK=64, 8 waves (2M x 4N), 512 threads.
// LDS: 2buf x 2 K-half x (A 16KB + B BN/16 KB). K-half h consumed in phases {0,1}/{2,3};
// stage 1 half per phase; counted vmcnt(2+BN/128) twice per tile, NEVER 0 until last tile.
// Swizzle: 16B slot s of row r holds global group s ^ (r&3) ^ ((r>>2)&3)  (2-way = free).
// EPI: 0 = bf16 store; 2 = bf16 silu(Aux_bf16)*acc (in-place ok); 4 = fp32 (acc + bf16 Aux)
template <int BN, int EPI>
__global__ __launch_bounds__(512, 2) void gemm8p_kernel(const u16* __restrict__ A,
                                                        const u16* __restrict__ W,
                                                        void* Out, const void* Aux,
                                                        int M, int N, int K) {
  constexpr int AHALF = 256 * 64;                // bytes per A K-half
  constexpr int BHALF = BN * 64;                 // bytes per B K-half
  constexpr int BLD   = BN / 128;                // B loads/thread per half (2|1)
  constexpr int NFR   = BN / 64;                 // B frags per wave (4|2)
  __shared__ __align__(16) char As[2 * 2 * AHALF];
  __shared__ __align__(16) char Bs[2 * 2 * BHALF];
  const int tid = threadIdx.x, wave = tid >> 6, lane = tid & 63;
  const int lm = lane & 15, lg = lane >> 4;

  int bx, by;
  {
    const int gx = gridDim.x;
    if ((gx & 7) == 0) {
      const int id = blockIdx.y * gx + blockIdx.x;
      const int xcd = id & 7, rank = id >> 3;
      const int cw = gx >> 3;
      bx = xcd * cw + rank % cw;
      by = rank / cw;
    } else { bx = blockIdx.x; by = blockIdx.y; }
  }
  const int m0 = by * 256, n0 = bx * BN;
  const int wm = wave >> 2, wn = wave & 3;

  f32x4 acc[8][NFR];
#pragma unroll
  for (int i = 0; i < 8; ++i)
#pragma unroll
    for (int j = 0; j < NFR; ++j) acc[i][j] = (f32x4){0.f, 0.f, 0.f, 0.f};

  const int nt = K >> 6;

  auto stA = [&](int buf, int k0, int h) {
#pragma unroll
    for (int p = 0; p < 2; ++p) {
      int idx = p * 512 + tid;
      int r = idx >> 2, s = idx & 3;
      int sg = s ^ (r & 3) ^ ((r >> 2) & 3);
      async_cp16(A + (size_t)(m0 + r) * K + k0 + h * 32 + sg * 8,
                 As + buf * (2 * AHALF) + h * AHALF + p * 8192 + wave * 1024);
    }
  };
  auto stB = [&](int buf, int k0, int h) {
#pragma unroll
    for (int p = 0; p < BLD; ++p) {
      int idx = p * 512 + tid;
      int r = idx >> 2, s = idx & 3;
      int sg = s ^ (r & 3) ^ ((r >> 2) & 3);
      async_cp16(W + (size_t)(n0 + r) * K + k0 + h * 32 + sg * 8,
                 Bs + buf * (2 * BHALF) + h * BHALF + p * 8192 + wave * 1024);
    }
  };

  bf16x8 a[4], b[NFR];
  auto lda = [&](int buf, int mg, int ks) {
#pragma unroll
    for (int i = 0; i < 4; ++i) {
      const int r = wm * 128 + mg * 64 + i * 16 + lm;
      const int sl = lg ^ (r & 3) ^ ((r >> 2) & 3);
      a[i] = *(const bf16x8*)(As + buf * (2 * AHALF) + ks * AHALF + r * 64 + sl * 16);
    }
  };
  auto ldb = [&](int buf, int ks) {
#pragma unroll
    for (int j = 0; j < NFR; ++j) {
      const int r = wn * (BN / 4) + j * 16 + lm;
      const int sl = lg ^ (r & 3) ^ ((r >> 2) & 3);
      b[j] = *(const bf16x8*)(Bs + buf * (2 * BHALF) + ks * BHALF + r * 64 + sl * 16);
    }
  };

#define SB __builtin_amdgcn_sched_barrier(0)
#define LGKM0() do { asm volatile("s_waitcnt lgkmcnt(0)" ::: "memory"); SB; } while (0)
#define VMC_WAIT()                                                          \
  do {                                                                      \
    if constexpr (BN == 256) asm volatile("s_waitcnt vmcnt(4)" ::: "memory"); \
    else                     asm volatile("s_waitcnt vmcnt(3)" ::: "memory"); \
    SB;                                                                     \
  } while (0)
#define MM(MB)                                                          \
  do {                                                                  \
    __builtin_amdgcn_s_setprio(1);                                      \
    _Pragma("unroll")                                                   \
    for (int i = 0; i < 4; ++i)                                         \
      _Pragma("unroll")                                                 \
      for (int j = 0; j < NFR; ++j)                                     \
        acc[(MB) + i][j] = __builtin_amdgcn_mfma_f32_16x16x32_bf16(     \
            a[i], b[j], acc[(MB) + i][j], 0, 0, 0);                     \
    __builtin_amdgcn_s_setprio(0);                                      \
    SB;                                                                 \
  } while (0)

  // prologue: tile 0 fully staged, drain once, sync
  stA(0, 0, 0); stB(0, 0, 0); stA(0, 0, 1); stB(0, 0, 1);
  asm volatile("s_waitcnt vmcnt(0)" ::: "memory");
  SB;
  barrier_nofence();

  for (int t = 0; t < nt; ++t) {
    const int cur = t & 1, nb = cur ^ 1;
    const bool pf = (t + 1 < nt);
    const int nk = (t + 1) << 6;

    // ---- P0: (mg0, ks0) ; stage A-h0(t+1)
    lda(cur, 0, 0); ldb(cur, 0);
    if (pf) stA(nb, nk, 0);
    SB;
    barrier_nofence();
    LGKM0();
    MM(0);
    barrier_nofence();

    // ---- P1: (mg1, ks0) ; stage B-h0(t+1)
    lda(cur, 1, 0);
    if (pf) stB(nb, nk, 0);
    SB;
    barrier_nofence();
    LGKM0();
    MM(4);
    // wait: cur half1 landed. pf: outstanding allowed = nb.Ah0+nb.Bh0 = 2+BLD.
    if (pf) { VMC_WAIT(); }
    else    { asm volatile("s_waitcnt vmcnt(0)" ::: "memory"); SB; }
    barrier_nofence();

    // ---- P2: (mg1, ks1) ; stage A-h1(t+1)
    lda(cur, 1, 1); ldb(cur, 1);
    if (pf) stA(nb, nk, 1);
    SB;
    barrier_nofence();
    LGKM0();
    MM(4);
    barrier_nofence();

    // ---- P3: (mg0, ks1) ; stage B-h1(t+1)
    lda(cur, 0, 1);
    if (pf) stB(nb, nk, 1);
    SB;
    barrier_nofence();
    LGKM0();
    MM(0);
    // wait: next tile half0 landed; outstanding allowed = nb.Ah1+nb.Bh1 = 2+BLD.
    if (pf) { VMC_WAIT(); }
    barrier_nofence();
  }
#undef MM
#undef VMC_WAIT
#undef LGKM0
#undef SB

  // epilogue: C/D layout col=lane&15, row=(lane>>4)*4+reg
#pragma unroll
  for (int i = 0; i < 8; ++i) {
    const int row_b = m0 + wm * 128 + i * 16 + lg * 4;
#pragma unroll
    for (int j = 0; j < NFR; ++j) {
      const int col = n0 + wn * (BN / 4) + j * 16 + lm;
#pragma unroll
      for (int r = 0; r < 4; ++r) {
        size_t idx = (size_t)(row_b + r) * N + col;
        float v = acc[i][j][r];
        if constexpr (EPI == 0) {
          ((u16*)Out)[idx] = f2bf(v);
        } else if constexpr (EPI == 2) {
          float a1 = bf2f(((const u16*)Aux)[idx]);
          float s = a1 / (1.0f + expf(-a1));   // silu
          ((u16*)Out)[idx] = f2bf(s * v);
        } else {
          ((float*)Out)[idx] = v + bf2f(((const u16*)Aux)[idx]);
        }
      }
    }
  }
}

// ---------------- Flash attention v5: QBLK=128, 8 waves, staged K+V, PAIRED q-tiles ----------------
__global__ __launch_bounds__(512) void attn_kernel(const u16* __restrict__ q,
                                                   const u16* __restrict__ kg,
                                                   const u16* __restrict__ vt,
                                                   u16* __restrict__ out) {
  __shared__ __align__(16) u16 Klds[64 * 128];
  __shared__ __align__(16) u16 Vlds[128 * 64];
  __shared__ __align__(16) u16 Plds[8][16 * 72];
  const int tid = threadIdx.x, wave = tid >> 6, lane = tid & 63;
  const int bh = blockIdx.y, b = bh >> 4, h = bh & 15;
  const float slope = exp2f(-0.5f * (float)(h + 1));
  const int lm = lane & 15, lg = lane >> 4;
  const int crow = lg * 4;
  const int NT = NS / 128;
  u16* pw = Plds[wave];

#pragma unroll 1
  for (int half = 0; half < 2; ++half) {
    const int qt = half == 0 ? (NT - 1 - (int)blockIdx.x) : (int)blockIdx.x;
    const int q0 = qt * 128;

    bf16x8 qf[4];
    {
      const int qrow = q0 + wave * 16 + lm;
      const u16* qbase = q + ((size_t)bh * NS + qrow) * NHD + lg * 8;
#pragma unroll
      for (int kc = 0; kc < 4; ++kc) qf[kc] = *(const bf16x8*)(qbase + kc * 32);
    }

    float Mr[4], Lr[4];
    f32x4 O[8];
#pragma unroll
    for (int r = 0; r < 4; ++r) { Mr[r] = -__builtin_inff(); Lr[r] = 0.f; }
#pragma unroll
    for (int t = 0; t < 8; ++t) O[t] = (f32x4){0.f, 0.f, 0.f, 0.f};

    const int ntiles = 2 * qt + 2;
    for (int t0 = 0; t0 < ntiles; ++t0) {
      const int kv0 = t0 * 64;
      __syncthreads();
#pragma unroll
      for (int p = 0; p < 2; ++p) {
        int X = p * 8192 + tid * 16;
        int kv = X >> 8;
        int sl = (X >> 4) & 15;
        const u16* src = kg + ((size_t)b * NS + kv0 + kv) * NHD + ((sl ^ (kv & 7)) * 8);
        async_cp16(src, (char*)Klds + p * 8192 + wave * 1024);
      }
#pragma unroll
      for (int p = 0; p < 2; ++p) {
        int X = p * 8192 + tid * 16;
        int d = X >> 7;
        int sl = (X >> 4) & 7;
        const u16* src = vt + ((size_t)b * 128 + d) * NS + kv0 + ((sl ^ (d & 7)) * 8);
        async_cp16(src, (char*)Vlds + p * 8192 + wave * 1024);
      }
      __syncthreads();

      f32x4 sc[4];
#pragma unroll
      for (int sub = 0; sub < 4; ++sub) sc[sub] = (f32x4){0.f, 0.f, 0.f, 0.f};
#pragma unroll
      for (int sub = 0; sub < 4; ++sub) {
        const int kv = sub * 16 + lm;
#pragma unroll
        for (int kc = 0; kc < 4; ++kc) {
          const int slot = (kc * 4 + lg) ^ (kv & 7);
          bf16x8 kf = *(const bf16x8*)((const char*)Klds + kv * 256 + slot * 16);
          sc[sub] = __builtin_amdgcn_mfma_f32_16x16x32_bf16(qf[kc], kf, sc[sub], 0, 0, 0);
        }
      }

      float esc[4], pp[4][4];
#pragma unroll
      for (int r = 0; r < 4; ++r) {
        const int sq = q0 + wave * 16 + crow + r;
        float v[4];
#pragma unroll
        for (int sub = 0; sub < 4; ++sub) {
          const int kc_ = kv0 + sub * 16 + lm;
          v[sub] = (kc_ <= sq) ? sc[sub][r] - slope * (float)(sq - kc_) : -1e9f;
        }
        float mx = fmaxf(fmaxf(v[0], v[1]), fmaxf(v[2], v[3]));
        mx = fmaxf(mx, __shfl_xor(mx, 1));
        mx = fmaxf(mx, __shfl_xor(mx, 2));
        mx = fmaxf(mx, __shfl_xor(mx, 4));
        mx = fmaxf(mx, __shfl_xor(mx, 8));
        const float newM = fmaxf(Mr[r], mx);
        esc[r] = __expf(Mr[r] - newM);
        float rs = 0.f;
#pragma unroll
        for (int sub = 0; sub < 4; ++sub) { pp[sub][r] = __expf(v[sub] - newM); rs += pp[sub][r]; }
        rs += __shfl_xor(rs, 1);
        rs += __shfl_xor(rs, 2);
        rs += __shfl_xor(rs, 4);
        rs += __shfl_xor(rs, 8);
        Lr[r] = Lr[r] * esc[r] + rs;
        Mr[r] = newM;
      }
#pragma unroll
      for (int t = 0; t < 8; ++t) {
        O[t][0] *= esc[0]; O[t][1] *= esc[1]; O[t][2] *= esc[2]; O[t][3] *= esc[3];
      }

#pragma unroll
      for (int sub = 0; sub < 4; ++sub)
#pragma unroll
        for (int r = 0; r < 4; ++r)
          pw[(crow + r) * 72 + sub * 16 + lm] = f2bf(pp[sub][r]);

      bf16x8 pa0 = *(const bf16x8*)&pw[lm * 72 + lg * 8];
      bf16x8 pa1 = *(const bf16x8*)&pw[lm * 72 + 32 + lg * 8];

#pragma unroll
      for (int dt = 0; dt < 8; ++dt) {
        const int d = dt * 16 + lm;
        const int s0 = (lg) ^ (d & 7);
        const int s1 = (4 + lg) ^ (d & 7);
        bf16x8 vf0 = *(const bf16x8*)((const char*)Vlds + d * 128 + s0 * 16);
        bf16x8 vf1 = *(const bf16x8*)((const char*)Vlds + d * 128 + s1 * 16);
        O[dt] = __builtin_amdgcn_mfma_f32_16x16x32_bf16(pa0, vf0, O[dt], 0, 0, 0);
        O[dt] = __builtin_amdgcn_mfma_f32_16x16x32_bf16(pa1, vf1, O[dt], 0, 0, 0);
      }
    }

#pragma unroll
    for (int dt = 0; dt < 8; ++dt) {
#pragma unroll
      for (int r = 0; r < 4; ++r) {
        const int sq = q0 + wave * 16 + crow + r;
        out[((size_t)b * NS + sq) * ND + h * NHD + dt * 16 + lm] = f2bf(O[dt][r] / Lr[r]);
      }
    }
  }
}

// ---------------- host ----------------
extern "C" void kernel_launch(void* const* d_in, const int* in_sizes, int n_in,
                              void* d_out, int out_size, void* d_ws, size_t ws_size,
                              hipStream_t stream) {
  const float* x   = (const float*)d_in[0];
  const float* wn1 = (const float*)d_in[2];
  const float* wn2 = (const float*)d_in[3];
  const float* qw  = (const float*)d_in[4];
  const float* kvw = (const float*)d_in[5];
  const float* ow  = (const float*)d_in[6];
  const float* w1  = (const float*)d_in[7];
  const float* w2  = (const float*)d_in[8];
  const float* w3  = (const float*)d_in[9];
  float* out = (float*)d_out;

  const size_t MiB = 1024 * 1024;
  const size_t NEED = 161 * MiB;
  if (ws_size < NEED) return;

  char* ws = (char*)d_ws;
  u16*   WQKV   = (u16*)(ws);                 // [0,9.2)
  u16*   AO     = (u16*)(ws + 16 * MiB);      // [16,32)
  u16*   OWB    = (u16*)(ws + 32 * MiB);      // [32,40)
  u16*   W1B    = (u16*)(ws);                 // [0,32)
  u16*   W2B    = (u16*)(ws + 32 * MiB);      // [32,64)
  u16*   W3B    = (u16*)(ws);                 // [0,32)
  u16*   QKVRAW = (u16*)(ws + 64 * MiB);      // [64,83)
  u16*   A1     = (u16*)(ws + 64 * MiB);      // [64,128)
  u16*   KB     = (u16*)(ws + 83 * MiB);      // [83,84)
  u16*   VT     = (u16*)(ws + 84 * MiB);      // [84,85)
  u16*   QB     = (u16*)(ws + 112 * MiB);     // [112,128)
  u16*   X2B    = (u16*)(ws + 128 * MiB);     // [128,144) bf16 residual
  u16*   Hbf    = (u16*)(ws + 144 * MiB);     // [144,160)
  float* COS    = (float*)(ws + 160 * MiB);
  float* SIN    = (float*)(ws + 160 * MiB + 512 * 1024);

  auto cvt = [&](const float* src, u16* dst, size_t n) {
    int n4 = (int)(n / 4);
    cvt_bf16_kernel<<<(n4 + 255) / 256, 256, 0, stream>>>(src, dst, n4);
  };

  rope_table_kernel<<<(NS * 64 + 255) / 256, 256, 0, stream>>>(COS, SIN);

  // h = rmsnorm(x, wn1)
  rmsnorm_kernel<0><<<NBS, 256, 0, stream>>>(x, wn1, Hbf);

  // qkv_raw = h @ [qw; kvw]^T   (fused, N=2304; gemm3: 576-block grid fills CUs)
  cvt(qw, WQKV, (size_t)ND * ND);
  cvt(kvw, WQKV + (size_t)ND * ND, (size_t)256 * ND);
  gemm3_kernel<0><<<dim3(NQKV / 128, NBS / 128), 256, 0, stream>>>(
      Hbf, WQKV, (void*)QKVRAW, nullptr, NBS, NQKV, ND);

  // rope
  rope_q_kernel<<<(NB * NS * NH * 64) / 256, 256, 0, stream>>>(QKVRAW, COS, SIN, QB);
  rope_kv_kernel<<<(NB * NS * 64) / 256, 256, 0, stream>>>(QKVRAW, COS, SIN, KB, VT);

  // attention -> AO   (QBLK=128, 8 waves, paired q-tiles)
  attn_kernel<<<dim3(NS / 256, NB * NH), 512, 0, stream>>>(QB, KB, VT, AO);

  // x2 = x + ao @ ow^T   (bf16 residual out)
  cvt(ow, OWB, (size_t)ND * ND);
  gemm3_kernel<3><<<dim3(ND / 128, NBS / 128), 256, 0, stream>>>(
      AO, OWB, (void*)X2B, (const void*)x, NBS, ND, ND);

  // h2 = rmsnorm(x2, wn2)
  rmsnorm_kernel<1><<<NBS, 256, 0, stream>>>(X2B, wn2, Hbf);

  // a1 = h2 @ w1^T       (8-phase, 512-block grid)
  cvt(w1, W1B, (size_t)NFF * ND);
  cvt(w2, W2B, (size_t)NFF * ND);
  gemm8p_kernel<256, 0><<<dim3(NFF / 256, NBS / 256), 512, 0, stream>>>(
      Hbf, W1B, (void*)A1, nullptr, NBS, NFF, ND);
  // g = silu(a1) * (h2 @ w2^T)   (8-phase, in-place over A1)
  gemm8p_kernel<256, 2><<<dim3(NFF / 256, NBS / 256), 512, 0, stream>>>(
      Hbf, W2B, (void*)A1, (const void*)A1, NBS, NFF, ND);

  // out = x2 + g @ w3^T   (8-phase BN=128: grid (16,16) = 256 blocks = 1/CU)
  cvt(w3, W3B, (size_t)ND * NFF);
  gemm8p_kernel<128, 4><<<dim3(ND / 128, NBS / 256), 512, 0, stream>>>(
      A1, W3B, (void*)out, (const void*)X2B, NBS, ND, NFF);
}

// Round 20
// 787.765 us; speedup vs baseline: 1.0405x; 1.0405x over previous
//
#include <hip/hip_runtime.h>
#include <stdint.h>

#define NB 2
#define NS 2048
#define ND 2048
#define NH 16
#define NHD 128
#define NFF 8192
#define NBS (NB*NS)   // 4096 rows
#define NQKV 2304     // 2048 q + 256 kv

typedef unsigned short u16;
typedef __attribute__((ext_vector_type(8))) short bf16x8;   // 8 bf16 = 4 VGPRs
typedef __attribute__((ext_vector_type(4))) unsigned short u16x4;
typedef __attribute__((ext_vector_type(4))) float f32x4;

__device__ __forceinline__ u16 f2bf(float f) {
  union { float f; unsigned u; } v; v.f = f;
  unsigned r = v.u + 0x7fffu + ((v.u >> 16) & 1u);   // RNE
  return (u16)(r >> 16);
}
__device__ __forceinline__ float bf2f(u16 h) {
  union { unsigned u; float f; } v; v.u = ((unsigned)h) << 16;
  return v.f;
}
__device__ __forceinline__ void async_cp16(const void* g, void* l) {
  __builtin_amdgcn_global_load_lds((const __attribute__((address_space(1))) void*)g,
                                   (__attribute__((address_space(3))) void*)l, 16, 0, 0);
}
__device__ __forceinline__ void barrier_nofence() {
  asm volatile("" ::: "memory");
  __builtin_amdgcn_s_barrier();
  asm volatile("" ::: "memory");
}

// ---------------- fp32 -> bf16 ----------------
__global__ void cvt_bf16_kernel(const float* __restrict__ in, u16* __restrict__ out, int n4) {
  int i = blockIdx.x * blockDim.x + threadIdx.x;
  if (i >= n4) return;
  float4 v = reinterpret_cast<const float4*>(in)[i];
  u16x4 o; o.x = f2bf(v.x); o.y = f2bf(v.y); o.z = f2bf(v.z); o.w = f2bf(v.w);
  reinterpret_cast<u16x4*>(out)[i] = o;
}

// ---------------- RMSNorm, one block per row. BF16IN: 0=fp32 input, 1=bf16 input ----------------
template <int BF16IN>
__global__ __launch_bounds__(256) void rmsnorm_kernel(const void* __restrict__ xin,
                                                      const float* __restrict__ w,
                                                      u16* __restrict__ out) {
  const int row = blockIdx.x, tid = threadIdx.x;
  float vs[8];
  if constexpr (BF16IN == 0) {
    const float* xr = (const float*)xin + (size_t)row * ND;
    float4 a = *reinterpret_cast<const float4*>(xr + tid * 8);
    float4 b = *reinterpret_cast<const float4*>(xr + tid * 8 + 4);
    vs[0]=a.x; vs[1]=a.y; vs[2]=a.z; vs[3]=a.w; vs[4]=b.x; vs[5]=b.y; vs[6]=b.z; vs[7]=b.w;
  } else {
    const u16* xr = (const u16*)xin + (size_t)row * ND;
    bf16x8 v = *reinterpret_cast<const bf16x8*>(xr + tid * 8);
#pragma unroll
    for (int j = 0; j < 8; ++j) vs[j] = bf2f((u16)v[j]);
  }
  float ss = 0.f;
#pragma unroll
  for (int j = 0; j < 8; ++j) ss += vs[j] * vs[j];
#pragma unroll
  for (int off = 32; off > 0; off >>= 1) ss += __shfl_down(ss, off);
  __shared__ float red[4];
  __shared__ float rinv_s;
  if ((tid & 63) == 0) red[tid >> 6] = ss;
  __syncthreads();
  if (tid == 0) rinv_s = rsqrtf((red[0] + red[1] + red[2] + red[3]) * (1.0f / ND) + 1e-6f);
  __syncthreads();
  const float rinv = rinv_s;
  const float* wr = w + tid * 8;
  u16* orow = out + (size_t)row * ND + tid * 8;
#pragma unroll
  for (int j = 0; j < 8; ++j) orow[j] = f2bf(vs[j] * rinv * wr[j]);
}

// ---------------- RoPE cos/sin table [S][64] ----------------
__global__ void rope_table_kernel(float* __restrict__ cosT, float* __restrict__ sinT) {
  int i = blockIdx.x * blockDim.x + threadIdx.x;
  if (i >= NS * 64) return;
  int s = i >> 6, d = i & 63;
  float freq = expf(-(float)d * (9.210340371976184f / 64.0f));  // 10000^(-d/64)
  float ang = (float)s * freq;
  cosT[i] = cosf(ang);
  sinT[i] = sinf(ang);
}

// ---- RoPE for Q: qkvraw [B,S,2304] bf16 -> [B*H, S, HD] bf16, pre-scaled 1/sqrt(HD) ----
__global__ void rope_q_kernel(const u16* __restrict__ qkvraw, const float* __restrict__ cosT,
                              const float* __restrict__ sinT, u16* __restrict__ qout) {
  int i = blockIdx.x * blockDim.x + threadIdx.x;
  if (i >= NB * NS * NH * 64) return;
  int d = i & 63, h = (i >> 6) & 15, s = (i >> 10) & (NS - 1), b = i >> 21;
  size_t rrow = ((size_t)(b * NS + s)) * NQKV + h * NHD;
  float t1 = bf2f(qkvraw[rrow + d]);
  float t2 = bf2f(qkvraw[rrow + d + 64]);
  float c = cosT[(s << 6) + d], sn = sinT[(s << 6) + d];
  const float scale = 0.08838834764831845f;  // 1/sqrt(128)
  size_t orow = (((size_t)(b * NH + h)) * NS + s) * NHD;
  qout[orow + d]      = f2bf((t1 * c - t2 * sn) * scale);
  qout[orow + d + 64] = f2bf((t2 * c + t1 * sn) * scale);
}

// ---- RoPE for K + transpose-copy V: qkvraw[...,2048+] -> k [B,S,HD], vt [B,128,S] ----
__global__ void rope_kv_kernel(const u16* __restrict__ qkvraw, const float* __restrict__ cosT,
                               const float* __restrict__ sinT, u16* __restrict__ kout,
                               u16* __restrict__ vtout) {
  int i = blockIdx.x * blockDim.x + threadIdx.x;
  if (i >= NB * NS * 64) return;
  int d = i & 63, s = (i >> 6) & (NS - 1), b = i >> 17;
  size_t rrow = ((size_t)(b * NS + s)) * NQKV + ND;
  float t1 = bf2f(qkvraw[rrow + d]);
  float t2 = bf2f(qkvraw[rrow + d + 64]);
  float c = cosT[(s << 6) + d], sn = sinT[(s << 6) + d];
  size_t orow = ((size_t)(b * NS + s)) * NHD;
  kout[orow + d]      = f2bf(t1 * c - t2 * sn);
  kout[orow + d + 64] = f2bf(t2 * c + t1 * sn);
  vtout[((size_t)(b * 128 + d)) * NS + s]      = qkvraw[rrow + 128 + d];
  vtout[((size_t)(b * 128 + d + 64)) * NS + s] = qkvraw[rrow + 128 + d + 64];
}

// ---------------- GEMM v9 (m97-structure + swizzle): C = A[M,K] @ W[N,K]^T (bf16) ----------------
// EPI: 0 = bf16 store; 2 = bf16 store silu(Aux_bf16)*acc (in-place ok);
//      3 = bf16 store of (acc + fp32 Aux); 4 = fp32 store of (acc + bf16 Aux)
template <int EPI>
__global__ __launch_bounds__(256) void gemm3_kernel(const u16* __restrict__ A,
                                                    const u16* __restrict__ W,
                                                    void* Out, const void* Aux,
                                                    int M, int N, int K) {
  __shared__ __align__(16) char As[128 * 128];
  __shared__ __align__(16) char Bs[128 * 128];
  const int tid = threadIdx.x, wave = tid >> 6, lane = tid & 63;
  const int lm = lane & 15, lg = lane >> 4;

  int bx, by;
  {
    const int gx = gridDim.x;
    if ((gx & 7) == 0) {
      const int id = blockIdx.y * gx + blockIdx.x;
      const int xcd = id & 7, rank = id >> 3;
      const int cw = gx >> 3;
      bx = xcd * cw + rank % cw;
      by = rank / cw;
    } else { bx = blockIdx.x; by = blockIdx.y; }
  }
  const int m0 = by * 128, n0 = bx * 128;
  const int wr = wave >> 1, wc = wave & 1;

  f32x4 acc[4][4];
#pragma unroll
  for (int i = 0; i < 4; ++i)
#pragma unroll
    for (int j = 0; j < 4; ++j) acc[i][j] = (f32x4){0.f, 0.f, 0.f, 0.f};

  for (int k0 = 0; k0 < K; k0 += 64) {
#pragma unroll
    for (int p = 0; p < 4; ++p) {
      int X = p * 4096 + tid * 16;
      int r = X >> 7;
      int sw = ((X >> 4) ^ (X >> 7)) & 7;
      async_cp16(A + (size_t)(m0 + r) * K + k0 + sw * 8, As + p * 4096 + wave * 1024);
      async_cp16(W + (size_t)(n0 + r) * K + k0 + sw * 8, Bs + p * 4096 + wave * 1024);
    }
    __syncthreads();
#pragma unroll
    for (int ks = 0; ks < 2; ++ks) {
      bf16x8 a[4], b[4];
#pragma unroll
      for (int i = 0; i < 4; ++i) {
        const int ra = wr * 64 + i * 16 + lm;
        const int sa = (ks * 4 + lg) ^ (ra & 7);
        a[i] = *(const bf16x8*)(As + ra * 128 + sa * 16);
        const int rb = wc * 64 + i * 16 + lm;
        const int sb = (ks * 4 + lg) ^ (rb & 7);
        b[i] = *(const bf16x8*)(Bs + rb * 128 + sb * 16);
      }
#pragma unroll
      for (int i = 0; i < 4; ++i)
#pragma unroll
        for (int j = 0; j < 4; ++j)
          acc[i][j] = __builtin_amdgcn_mfma_f32_16x16x32_bf16(a[i], b[j], acc[i][j], 0, 0, 0);
    }
    __syncthreads();
  }

#pragma unroll
  for (int i = 0; i < 4; ++i) {
    const int row_b = m0 + wr * 64 + i * 16 + lg * 4;
#pragma unroll
    for (int j = 0; j < 4; ++j) {
      const int col = n0 + wc * 64 + j * 16 + lm;
#pragma unroll
      for (int r = 0; r < 4; ++r) {
        size_t idx = (size_t)(row_b + r) * N + col;
        float v = acc[i][j][r];
        if constexpr (EPI == 0) {
          ((u16*)Out)[idx] = f2bf(v);
        } else if constexpr (EPI == 2) {
          float a1 = bf2f(((const u16*)Aux)[idx]);
          float s = a1 / (1.0f + expf(-a1));   // silu
          ((u16*)Out)[idx] = f2bf(s * v);
        } else if constexpr (EPI == 3) {
          ((u16*)Out)[idx] = f2bf(v + ((const float*)Aux)[idx]);
        } else {
          ((float*)Out)[idx] = v + bf2f(((const u16*)Aux)[idx]);
        }
      }
    }
  }
}

// ---------------- GEMM 8-phase (K-split halves, counted vmcnt): C = A @ W^T bf16 ----------------
// 256x256 tile, BK=64, 8 waves (2M x 4N), 512 threads, LDS 128KB (2buf x 2 K-half x A,B).
// Used ONLY for W1 (N=8192, EPI0) — the configuration its +6.5% win was measured in.
__global__ __launch_bounds__(512, 2) void gemm8p_kernel(const u16* __restrict__ A,
                                                        const u16* __restrict__ W,
                                                        u16* __restrict__ Out,
                                                        int M, int N, int K) {
  constexpr int HALF = 256 * 64;                 // bytes per K-half (256 rows x 64B)
  __shared__ __align__(16) char As[2 * 2 * HALF];  // [buf][half] 64KB
  __shared__ __align__(16) char Bs[2 * 2 * HALF];  // 64KB
  const int tid = threadIdx.x, wave = tid >> 6, lane = tid & 63;
  const int lm = lane & 15, lg = lane >> 4;

  int bx, by;
  {
    const int gx = gridDim.x;
    if ((gx & 7) == 0) {
      const int id = blockIdx.y * gx + blockIdx.x;
      const int xcd = id & 7, rank = id >> 3;
      const int cw = gx >> 3;
      bx = xcd * cw + rank % cw;
      by = rank / cw;
    } else { bx = blockIdx.x; by = blockIdx.y; }
  }
  const int m0 = by * 256, n0 = bx * 256;
  const int wm = wave >> 2, wn = wave & 3;

  f32x4 acc[8][4];
#pragma unroll
  for (int i = 0; i < 8; ++i)
#pragma unroll
    for (int j = 0; j < 4; ++j) acc[i][j] = (f32x4){0.f, 0.f, 0.f, 0.f};

  const int nt = K >> 6;

  auto stA = [&](int buf, int k0, int h) {
#pragma unroll
    for (int p = 0; p < 2; ++p) {
      int idx = p * 512 + tid;
      int r = idx >> 2, s = idx & 3;
      int sg = s ^ (r & 3) ^ ((r >> 2) & 3);
      async_cp16(A + (size_t)(m0 + r) * K + k0 + h * 32 + sg * 8,
                 As + buf * (2 * HALF) + h * HALF + p * 8192 + wave * 1024);
    }
  };
  auto stB = [&](int buf, int k0, int h) {
#pragma unroll
    for (int p = 0; p < 2; ++p) {
      int idx = p * 512 + tid;
      int r = idx >> 2, s = idx & 3;
      int sg = s ^ (r & 3) ^ ((r >> 2) & 3);
      async_cp16(W + (size_t)(n0 + r) * K + k0 + h * 32 + sg * 8,
                 Bs + buf * (2 * HALF) + h * HALF + p * 8192 + wave * 1024);
    }
  };

  bf16x8 a[4], b[4];
  auto lda = [&](int buf, int mg, int ks) {
#pragma unroll
    for (int i = 0; i < 4; ++i) {
      const int r = wm * 128 + mg * 64 + i * 16 + lm;
      const int sl = lg ^ (r & 3) ^ ((r >> 2) & 3);
      a[i] = *(const bf16x8*)(As + buf * (2 * HALF) + ks * HALF + r * 64 + sl * 16);
    }
  };
  auto ldb = [&](int buf, int ks) {
#pragma unroll
    for (int j = 0; j < 4; ++j) {
      const int r = wn * 64 + j * 16 + lm;
      const int sl = lg ^ (r & 3) ^ ((r >> 2) & 3);
      b[j] = *(const bf16x8*)(Bs + buf * (2 * HALF) + ks * HALF + r * 64 + sl * 16);
    }
  };

#define SB __builtin_amdgcn_sched_barrier(0)
#define LGKM0() do { asm volatile("s_waitcnt lgkmcnt(0)" ::: "memory"); SB; } while (0)
#define MM(MB)                                                          \
  do {                                                                  \
    __builtin_amdgcn_s_setprio(1);                                      \
    _Pragma("unroll")                                                   \
    for (int i = 0; i < 4; ++i)                                         \
      _Pragma("unroll")                                                 \
      for (int j = 0; j < 4; ++j)                                       \
        acc[(MB) + i][j] = __builtin_amdgcn_mfma_f32_16x16x32_bf16(     \
            a[i], b[j], acc[(MB) + i][j], 0, 0, 0);                     \
    __builtin_amdgcn_s_setprio(0);                                      \
    SB;                                                                 \
  } while (0)

  // prologue: tile 0 fully staged, drain once, sync
  stA(0, 0, 0); stB(0, 0, 0); stA(0, 0, 1); stB(0, 0, 1);
  asm volatile("s_waitcnt vmcnt(0)" ::: "memory");
  SB;
  barrier_nofence();

  for (int t = 0; t < nt; ++t) {
    const int cur = t & 1, nb = cur ^ 1;
    const bool pf = (t + 1 < nt);
    const int nk = (t + 1) << 6;

    // ---- P0: (mg0, ks0) ; stage A-h0(t+1)
    lda(cur, 0, 0); ldb(cur, 0);
    if (pf) stA(nb, nk, 0);
    SB;
    barrier_nofence();
    LGKM0();
    MM(0);
    barrier_nofence();

    // ---- P1: (mg1, ks0) ; stage B-h0(t+1)
    lda(cur, 1, 0);
    if (pf) stB(nb, nk, 0);
    SB;
    barrier_nofence();
    LGKM0();
    MM(4);
    if (pf) asm volatile("s_waitcnt vmcnt(4)" ::: "memory");
    else    asm volatile("s_waitcnt vmcnt(0)" ::: "memory");
    SB;
    barrier_nofence();

    // ---- P2: (mg1, ks1) ; stage A-h1(t+1)
    lda(cur, 1, 1); ldb(cur, 1);
    if (pf) stA(nb, nk, 1);
    SB;
    barrier_nofence();
    LGKM0();
    MM(4);
    barrier_nofence();

    // ---- P3: (mg0, ks1) ; stage B-h1(t+1)
    lda(cur, 0, 1);
    if (pf) stB(nb, nk, 1);
    SB;
    barrier_nofence();
    LGKM0();
    MM(0);
    if (pf) { asm volatile("s_waitcnt vmcnt(4)" ::: "memory"); SB; }
    barrier_nofence();
  }
#undef MM
#undef LGKM0
#undef SB

  // epilogue: C/D layout col=lane&15, row=(lane>>4)*4+reg ; bf16 store
#pragma unroll
  for (int i = 0; i < 8; ++i) {
    const int row_b = m0 + wm * 128 + i * 16 + lg * 4;
#pragma unroll
    for (int j = 0; j < 4; ++j) {
      const int col = n0 + wn * 64 + j * 16 + lm;
#pragma unroll
      for (int r = 0; r < 4; ++r) {
        size_t idx = (size_t)(row_b + r) * N + col;
        Out[idx] = f2bf(acc[i][j][r]);
      }
    }
  }
}

// ---------------- Flash attention v5: QBLK=128, 8 waves, staged K+V, PAIRED q-tiles ----------------
__global__ __launch_bounds__(512) void attn_kernel(const u16* __restrict__ q,
                                                   const u16* __restrict__ kg,
                                                   const u16* __restrict__ vt,
                                                   u16* __restrict__ out) {
  __shared__ __align__(16) u16 Klds[64 * 128];
  __shared__ __align__(16) u16 Vlds[128 * 64];
  __shared__ __align__(16) u16 Plds[8][16 * 72];
  const int tid = threadIdx.x, wave = tid >> 6, lane = tid & 63;
  const int bh = blockIdx.y, b = bh >> 4, h = bh & 15;
  const float slope = exp2f(-0.5f * (float)(h + 1));
  const int lm = lane & 15, lg = lane >> 4;
  const int crow = lg * 4;
  const int NT = NS / 128;
  u16* pw = Plds[wave];

#pragma unroll 1
  for (int half = 0; half < 2; ++half) {
    const int qt = half == 0 ? (NT - 1 - (int)blockIdx.x) : (int)blockIdx.x;
    const int q0 = qt * 128;

    bf16x8 qf[4];
    {
      const int qrow = q0 + wave * 16 + lm;
      const u16* qbase = q + ((size_t)bh * NS + qrow) * NHD + lg * 8;
#pragma unroll
      for (int kc = 0; kc < 4; ++kc) qf[kc] = *(const bf16x8*)(qbase + kc * 32);
    }

    float Mr[4], Lr[4];
    f32x4 O[8];
#pragma unroll
    for (int r = 0; r < 4; ++r) { Mr[r] = -__builtin_inff(); Lr[r] = 0.f; }
#pragma unroll
    for (int t = 0; t < 8; ++t) O[t] = (f32x4){0.f, 0.f, 0.f, 0.f};

    const int ntiles = 2 * qt + 2;
    for (int t0 = 0; t0 < ntiles; ++t0) {
      const int kv0 = t0 * 64;
      __syncthreads();
#pragma unroll
      for (int p = 0; p < 2; ++p) {
        int X = p * 8192 + tid * 16;
        int kv = X >> 8;
        int sl = (X >> 4) & 15;
        const u16* src = kg + ((size_t)b * NS + kv0 + kv) * NHD + ((sl ^ (kv & 7)) * 8);
        async_cp16(src, (char*)Klds + p * 8192 + wave * 1024);
      }
#pragma unroll
      for (int p = 0; p < 2; ++p) {
        int X = p * 8192 + tid * 16;
        int d = X >> 7;
        int sl = (X >> 4) & 7;
        const u16* src = vt + ((size_t)b * 128 + d) * NS + kv0 + ((sl ^ (d & 7)) * 8);
        async_cp16(src, (char*)Vlds + p * 8192 + wave * 1024);
      }
      __syncthreads();

      f32x4 sc[4];
#pragma unroll
      for (int sub = 0; sub < 4; ++sub) sc[sub] = (f32x4){0.f, 0.f, 0.f, 0.f};
#pragma unroll
      for (int sub = 0; sub < 4; ++sub) {
        const int kv = sub * 16 + lm;
#pragma unroll
        for (int kc = 0; kc < 4; ++kc) {
          const int slot = (kc * 4 + lg) ^ (kv & 7);
          bf16x8 kf = *(const bf16x8*)((const char*)Klds + kv * 256 + slot * 16);
          sc[sub] = __builtin_amdgcn_mfma_f32_16x16x32_bf16(qf[kc], kf, sc[sub], 0, 0, 0);
        }
      }

      float esc[4], pp[4][4];
#pragma unroll
      for (int r = 0; r < 4; ++r) {
        const int sq = q0 + wave * 16 + crow + r;
        float v[4];
#pragma unroll
        for (int sub = 0; sub < 4; ++sub) {
          const int kc_ = kv0 + sub * 16 + lm;
          v[sub] = (kc_ <= sq) ? sc[sub][r] - slope * (float)(sq - kc_) : -1e9f;
        }
        float mx = fmaxf(fmaxf(v[0], v[1]), fmaxf(v[2], v[3]));
        mx = fmaxf(mx, __shfl_xor(mx, 1));
        mx = fmaxf(mx, __shfl_xor(mx, 2));
        mx = fmaxf(mx, __shfl_xor(mx, 4));
        mx = fmaxf(mx, __shfl_xor(mx, 8));
        const float newM = fmaxf(Mr[r], mx);
        esc[r] = __expf(Mr[r] - newM);
        float rs = 0.f;
#pragma unroll
        for (int sub = 0; sub < 4; ++sub) { pp[sub][r] = __expf(v[sub] - newM); rs += pp[sub][r]; }
        rs += __shfl_xor(rs, 1);
        rs += __shfl_xor(rs, 2);
        rs += __shfl_xor(rs, 4);
        rs += __shfl_xor(rs, 8);
        Lr[r] = Lr[r] * esc[r] + rs;
        Mr[r] = newM;
      }
#pragma unroll
      for (int t = 0; t < 8; ++t) {
        O[t][0] *= esc[0]; O[t][1] *= esc[1]; O[t][2] *= esc[2]; O[t][3] *= esc[3];
      }

#pragma unroll
      for (int sub = 0; sub < 4; ++sub)
#pragma unroll
        for (int r = 0; r < 4; ++r)
          pw[(crow + r) * 72 + sub * 16 + lm] = f2bf(pp[sub][r]);

      bf16x8 pa0 = *(const bf16x8*)&pw[lm * 72 + lg * 8];
      bf16x8 pa1 = *(const bf16x8*)&pw[lm * 72 + 32 + lg * 8];

#pragma unroll
      for (int dt = 0; dt < 8; ++dt) {
        const int d = dt * 16 + lm;
        const int s0 = (lg) ^ (d & 7);
        const int s1 = (4 + lg) ^ (d & 7);
        bf16x8 vf0 = *(const bf16x8*)((const char*)Vlds + d * 128 + s0 * 16);
        bf16x8 vf1 = *(const bf16x8*)((const char*)Vlds + d * 128 + s1 * 16);
        O[dt] = __builtin_amdgcn_mfma_f32_16x16x32_bf16(pa0, vf0, O[dt], 0, 0, 0);
        O[dt] = __builtin_amdgcn_mfma_f32_16x16x32_bf16(pa1, vf1, O[dt], 0, 0, 0);
      }
    }

#pragma unroll
    for (int dt = 0; dt < 8; ++dt) {
#pragma unroll
      for (int r = 0; r < 4; ++r) {
        const int sq = q0 + wave * 16 + crow + r;
        out[((size_t)b * NS + sq) * ND + h * NHD + dt * 16 + lm] = f2bf(O[dt][r] / Lr[r]);
      }
    }
  }
}

// ---------------- host ----------------
extern "C" void kernel_launch(void* const* d_in, const int* in_sizes, int n_in,
                              void* d_out, int out_size, void* d_ws, size_t ws_size,
                              hipStream_t stream) {
  const float* x   = (const float*)d_in[0];
  const float* wn1 = (const float*)d_in[2];
  const float* wn2 = (const float*)d_in[3];
  const float* qw  = (const float*)d_in[4];
  const float* kvw = (const float*)d_in[5];
  const float* ow  = (const float*)d_in[6];
  const float* w1  = (const float*)d_in[7];
  const float* w2  = (const float*)d_in[8];
  const float* w3  = (const float*)d_in[9];
  float* out = (float*)d_out;

  const size_t MiB = 1024 * 1024;
  const size_t NEED = 161 * MiB;
  if (ws_size < NEED) return;

  char* ws = (char*)d_ws;
  u16*   WQKV   = (u16*)(ws);                 // [0,9.2)
  u16*   AO     = (u16*)(ws + 16 * MiB);      // [16,32)
  u16*   OWB    = (u16*)(ws + 32 * MiB);      // [32,40)
  u16*   W1B    = (u16*)(ws);                 // [0,32)
  u16*   W2B    = (u16*)(ws + 32 * MiB);      // [32,64)
  u16*   W3B    = (u16*)(ws);                 // [0,32)
  u16*   QKVRAW = (u16*)(ws + 64 * MiB);      // [64,83)
  u16*   A1     = (u16*)(ws + 64 * MiB);      // [64,128)
  u16*   KB     = (u16*)(ws + 83 * MiB);      // [83,84)
  u16*   VT     = (u16*)(ws + 84 * MiB);      // [84,85)
  u16*   QB     = (u16*)(ws + 112 * MiB);     // [112,128)
  u16*   X2B    = (u16*)(ws + 128 * MiB);     // [128,144) bf16 residual
  u16*   Hbf    = (u16*)(ws + 144 * MiB);     // [144,160)
  float* COS    = (float*)(ws + 160 * MiB);
  float* SIN    = (float*)(ws + 160 * MiB + 512 * 1024);

  auto cvt = [&](const float* src, u16* dst, size_t n) {
    int n4 = (int)(n / 4);
    cvt_bf16_kernel<<<(n4 + 255) / 256, 256, 0, stream>>>(src, dst, n4);
  };

  rope_table_kernel<<<(NS * 64 + 255) / 256, 256, 0, stream>>>(COS, SIN);

  // h = rmsnorm(x, wn1)
  rmsnorm_kernel<0><<<NBS, 256, 0, stream>>>(x, wn1, Hbf);

  // qkv_raw = h @ [qw; kvw]^T   (fused, N=2304)
  cvt(qw, WQKV, (size_t)ND * ND);
  cvt(kvw, WQKV + (size_t)ND * ND, (size_t)256 * ND);
  gemm3_kernel<0><<<dim3(NQKV / 128, NBS / 128), 256, 0, stream>>>(
      Hbf, WQKV, (void*)QKVRAW, nullptr, NBS, NQKV, ND);

  // rope
  rope_q_kernel<<<(NB * NS * NH * 64) / 256, 256, 0, stream>>>(QKVRAW, COS, SIN, QB);
  rope_kv_kernel<<<(NB * NS * 64) / 256, 256, 0, stream>>>(QKVRAW, COS, SIN, KB, VT);

  // attention -> AO   (QBLK=128, 8 waves, paired q-tiles)
  attn_kernel<<<dim3(NS / 256, NB * NH), 512, 0, stream>>>(QB, KB, VT, AO);

  // x2 = x + ao @ ow^T   (bf16 residual out)
  cvt(ow, OWB, (size_t)ND * ND);
  gemm3_kernel<3><<<dim3(ND / 128, NBS / 128), 256, 0, stream>>>(
      AO, OWB, (void*)X2B, (const void*)x, NBS, ND, ND);

  // h2 = rmsnorm(x2, wn2)
  rmsnorm_kernel<1><<<NBS, 256, 0, stream>>>(X2B, wn2, Hbf);

  // a1 = h2 @ w1^T   (8-phase — the configuration its win was measured in)
  cvt(w1, W1B, (size_t)NFF * ND);
  cvt(w2, W2B, (size_t)NFF * ND);
  gemm8p_kernel<<<dim3(NFF / 256, NBS / 256), 512, 0, stream>>>(
      Hbf, W1B, A1, NBS, NFF, ND);
  // g = silu(a1) * (h2 @ w2^T)  (gemm3, in-place over A1)
  gemm3_kernel<2><<<dim3(NFF / 128, NBS / 128), 256, 0, stream>>>(
      Hbf, W2B, (void*)A1, (const void*)A1, NBS, NFF, ND);

  // out = x2 + g @ w3^T   (gemm3)
  cvt(w3, W3B, (size_t)ND * NFF);
  gemm3_kernel<4><<<dim3(ND / 128, NBS / 128), 256, 0, stream>>>(
      A1, W3B, (void*)out, (const void*)X2B, NBS, ND, NFF);
}

// Round 21
// 780.618 us; speedup vs baseline: 1.0501x; 1.0092x over previous
//
#include <hip/hip_runtime.h>
#include <stdint.h>

#define NB 2
#define NS 2048
#define ND 2048
#define NH 16
#define NHD 128
#define NFF 8192
#define NBS (NB*NS)   // 4096 rows
#define NQKV 2304     // 2048 q + 256 kv

typedef unsigned short u16;
typedef __attribute__((ext_vector_type(8))) short bf16x8;   // 8 bf16 = 4 VGPRs
typedef __attribute__((ext_vector_type(4))) unsigned short u16x4;
typedef __attribute__((ext_vector_type(4))) float f32x4;

__device__ __forceinline__ u16 f2bf(float f) {
  union { float f; unsigned u; } v; v.f = f;
  unsigned r = v.u + 0x7fffu + ((v.u >> 16) & 1u);   // RNE
  return (u16)(r >> 16);
}
__device__ __forceinline__ float bf2f(u16 h) {
  union { unsigned u; float f; } v; v.u = ((unsigned)h) << 16;
  return v.f;
}
__device__ __forceinline__ void async_cp16(const void* g, void* l) {
  __builtin_amdgcn_global_load_lds((const __attribute__((address_space(1))) void*)g,
                                   (__attribute__((address_space(3))) void*)l, 16, 0, 0);
}
__device__ __forceinline__ void barrier_nofence() {
  asm volatile("" ::: "memory");
  __builtin_amdgcn_s_barrier();
  asm volatile("" ::: "memory");
}

// ---------------- fp32 -> bf16, up to 3 segments in one dispatch ----------------
__global__ void cvt3_bf16_kernel(const float* __restrict__ s0, u16* __restrict__ d0, int n0,
                                 const float* __restrict__ s1, u16* __restrict__ d1, int n1,
                                 const float* __restrict__ s2, u16* __restrict__ d2, int n2) {
  int i = blockIdx.x * blockDim.x + threadIdx.x;   // float4 index
  const float* src; u16* dst; int k;
  if (i < n0)                { src = s0; dst = d0; k = i; }
  else if (i < n0 + n1)      { src = s1; dst = d1; k = i - n0; }
  else if (i < n0 + n1 + n2) { src = s2; dst = d2; k = i - n0 - n1; }
  else return;
  float4 v = reinterpret_cast<const float4*>(src)[k];
  u16x4 o; o.x = f2bf(v.x); o.y = f2bf(v.y); o.z = f2bf(v.z); o.w = f2bf(v.w);
  reinterpret_cast<u16x4*>(dst)[k] = o;
}

// ---------------- RMSNorm, one block per row. BF16IN: 0=fp32 input, 1=bf16 input ----------------
template <int BF16IN>
__global__ __launch_bounds__(256) void rmsnorm_kernel(const void* __restrict__ xin,
                                                      const float* __restrict__ w,
                                                      u16* __restrict__ out) {
  const int row = blockIdx.x, tid = threadIdx.x;
  float vs[8];
  if constexpr (BF16IN == 0) {
    const float* xr = (const float*)xin + (size_t)row * ND;
    float4 a = *reinterpret_cast<const float4*>(xr + tid * 8);
    float4 b = *reinterpret_cast<const float4*>(xr + tid * 8 + 4);
    vs[0]=a.x; vs[1]=a.y; vs[2]=a.z; vs[3]=a.w; vs[4]=b.x; vs[5]=b.y; vs[6]=b.z; vs[7]=b.w;
  } else {
    const u16* xr = (const u16*)xin + (size_t)row * ND;
    bf16x8 v = *reinterpret_cast<const bf16x8*>(xr + tid * 8);
#pragma unroll
    for (int j = 0; j < 8; ++j) vs[j] = bf2f((u16)v[j]);
  }
  float ss = 0.f;
#pragma unroll
  for (int j = 0; j < 8; ++j) ss += vs[j] * vs[j];
#pragma unroll
  for (int off = 32; off > 0; off >>= 1) ss += __shfl_down(ss, off);
  __shared__ float red[4];
  __shared__ float rinv_s;
  if ((tid & 63) == 0) red[tid >> 6] = ss;
  __syncthreads();
  if (tid == 0) rinv_s = rsqrtf((red[0] + red[1] + red[2] + red[3]) * (1.0f / ND) + 1e-6f);
  __syncthreads();
  const float rinv = rinv_s;
  const float* wr = w + tid * 8;
  u16* orow = out + (size_t)row * ND + tid * 8;
#pragma unroll
  for (int j = 0; j < 8; ++j) orow[j] = f2bf(vs[j] * rinv * wr[j]);
}

// ---------------- RoPE cos/sin table [S][64] ----------------
__global__ void rope_table_kernel(float* __restrict__ cosT, float* __restrict__ sinT) {
  int i = blockIdx.x * blockDim.x + threadIdx.x;
  if (i >= NS * 64) return;
  int s = i >> 6, d = i & 63;
  float freq = expf(-(float)d * (9.210340371976184f / 64.0f));  // 10000^(-d/64)
  float ang = (float)s * freq;
  cosT[i] = cosf(ang);
  sinT[i] = sinf(ang);
}

// ---- RoPE for Q: qkvraw [B,S,2304] bf16 -> [B*H, S, HD] bf16, pre-scaled 1/sqrt(HD) ----
__global__ void rope_q_kernel(const u16* __restrict__ qkvraw, const float* __restrict__ cosT,
                              const float* __restrict__ sinT, u16* __restrict__ qout) {
  int i = blockIdx.x * blockDim.x + threadIdx.x;
  if (i >= NB * NS * NH * 64) return;
  int d = i & 63, h = (i >> 6) & 15, s = (i >> 10) & (NS - 1), b = i >> 21;
  size_t rrow = ((size_t)(b * NS + s)) * NQKV + h * NHD;
  float t1 = bf2f(qkvraw[rrow + d]);
  float t2 = bf2f(qkvraw[rrow + d + 64]);
  float c = cosT[(s << 6) + d], sn = sinT[(s << 6) + d];
  const float scale = 0.08838834764831845f;  // 1/sqrt(128)
  size_t orow = (((size_t)(b * NH + h)) * NS + s) * NHD;
  qout[orow + d]      = f2bf((t1 * c - t2 * sn) * scale);
  qout[orow + d + 64] = f2bf((t2 * c + t1 * sn) * scale);
}

// ---- RoPE for K + transpose-copy V: qkvraw[...,2048+] -> k [B,S,HD], vt [B,128,S] ----
__global__ void rope_kv_kernel(const u16* __restrict__ qkvraw, const float* __restrict__ cosT,
                               const float* __restrict__ sinT, u16* __restrict__ kout,
                               u16* __restrict__ vtout) {
  int i = blockIdx.x * blockDim.x + threadIdx.x;
  if (i >= NB * NS * 64) return;
  int d = i & 63, s = (i >> 6) & (NS - 1), b = i >> 17;
  size_t rrow = ((size_t)(b * NS + s)) * NQKV + ND;
  float t1 = bf2f(qkvraw[rrow + d]);
  float t2 = bf2f(qkvraw[rrow + d + 64]);
  float c = cosT[(s << 6) + d], sn = sinT[(s << 6) + d];
  size_t orow = ((size_t)(b * NS + s)) * NHD;
  kout[orow + d]      = f2bf(t1 * c - t2 * sn);
  kout[orow + d + 64] = f2bf(t2 * c + t1 * sn);
  vtout[((size_t)(b * 128 + d)) * NS + s]      = qkvraw[rrow + 128 + d];
  vtout[((size_t)(b * 128 + d + 64)) * NS + s] = qkvraw[rrow + 128 + d + 64];
}

// ---------------- GEMM v9 (m97-structure + swizzle): C = A[M,K] @ W[N,K]^T (bf16) ----------------
// EPI: 0 = bf16 store; 2 = bf16 store silu(Aux_bf16)*acc (in-place ok);
//      3 = bf16 store of (acc + fp32 Aux); 4 = fp32 store of (acc + bf16 Aux)
// SWAP: 0 = gridDim.x indexes N (default); 1 = gridDim.x indexes M (for XCD remap
//       when N-tiles % 8 != 0 but M-tiles % 8 == 0, e.g. QKV N=2304).
template <int EPI, int SWAP = 0>
__global__ __launch_bounds__(256) void gemm3_kernel(const u16* __restrict__ A,
                                                    const u16* __restrict__ W,
                                                    void* Out, const void* Aux,
                                                    int M, int N, int K) {
  __shared__ __align__(16) char As[128 * 128];
  __shared__ __align__(16) char Bs[128 * 128];
  const int tid = threadIdx.x, wave = tid >> 6, lane = tid & 63;
  const int lm = lane & 15, lg = lane >> 4;

  int bx, by;
  {
    const int gx = gridDim.x;
    if ((gx & 7) == 0) {
      const int id = blockIdx.y * gx + blockIdx.x;
      const int xcd = id & 7, rank = id >> 3;
      const int cw = gx >> 3;
      bx = xcd * cw + rank % cw;
      by = rank / cw;
    } else { bx = blockIdx.x; by = blockIdx.y; }
  }
  const int m0 = (SWAP ? bx : by) * 128, n0 = (SWAP ? by : bx) * 128;
  const int wr = wave >> 1, wc = wave & 1;

  f32x4 acc[4][4];
#pragma unroll
  for (int i = 0; i < 4; ++i)
#pragma unroll
    for (int j = 0; j < 4; ++j) acc[i][j] = (f32x4){0.f, 0.f, 0.f, 0.f};

  for (int k0 = 0; k0 < K; k0 += 64) {
#pragma unroll
    for (int p = 0; p < 4; ++p) {
      int X = p * 4096 + tid * 16;
      int r = X >> 7;
      int sw = ((X >> 4) ^ (X >> 7)) & 7;
      async_cp16(A + (size_t)(m0 + r) * K + k0 + sw * 8, As + p * 4096 + wave * 1024);
      async_cp16(W + (size_t)(n0 + r) * K + k0 + sw * 8, Bs + p * 4096 + wave * 1024);
    }
    __syncthreads();
#pragma unroll
    for (int ks = 0; ks < 2; ++ks) {
      bf16x8 a[4], b[4];
#pragma unroll
      for (int i = 0; i < 4; ++i) {
        const int ra = wr * 64 + i * 16 + lm;
        const int sa = (ks * 4 + lg) ^ (ra & 7);
        a[i] = *(const bf16x8*)(As + ra * 128 + sa * 16);
        const int rb = wc * 64 + i * 16 + lm;
        const int sb = (ks * 4 + lg) ^ (rb & 7);
        b[i] = *(const bf16x8*)(Bs + rb * 128 + sb * 16);
      }
#pragma unroll
      for (int i = 0; i < 4; ++i)
#pragma unroll
        for (int j = 0; j < 4; ++j)
          acc[i][j] = __builtin_amdgcn_mfma_f32_16x16x32_bf16(a[i], b[j], acc[i][j], 0, 0, 0);
    }
    __syncthreads();
  }

#pragma unroll
  for (int i = 0; i < 4; ++i) {
    const int row_b = m0 + wr * 64 + i * 16 + lg * 4;
#pragma unroll
    for (int j = 0; j < 4; ++j) {
      const int col = n0 + wc * 64 + j * 16 + lm;
#pragma unroll
      for (int r = 0; r < 4; ++r) {
        size_t idx = (size_t)(row_b + r) * N + col;
        float v = acc[i][j][r];
        if constexpr (EPI == 0) {
          ((u16*)Out)[idx] = f2bf(v);
        } else if constexpr (EPI == 2) {
          float a1 = bf2f(((const u16*)Aux)[idx]);
          float s = a1 / (1.0f + expf(-a1));   // silu
          ((u16*)Out)[idx] = f2bf(s * v);
        } else if constexpr (EPI == 3) {
          ((u16*)Out)[idx] = f2bf(v + ((const float*)Aux)[idx]);
        } else {
          ((float*)Out)[idx] = v + bf2f(((const u16*)Aux)[idx]);
        }
      }
    }
  }
}

// ---------------- GEMM 8-phase (K-split halves, counted vmcnt): C = A @ W^T bf16 ----------------
// 256x256 tile, BK=64, 8 waves (2M x 4N), 512 threads, LDS 128KB (2buf x 2 K-half x A,B).
// Used ONLY for W1 (N=8192, EPI0) — the configuration its +6.5% win was measured in.
__global__ __launch_bounds__(512, 2) void gemm8p_kernel(const u16* __restrict__ A,
                                                        const u16* __restrict__ W,
                                                        u16* __restrict__ Out,
                                                        int M, int N, int K) {
  constexpr int HALF = 256 * 64;                 // bytes per K-half (256 rows x 64B)
  __shared__ __align__(16) char As[2 * 2 * HALF];  // [buf][half] 64KB
  __shared__ __align__(16) char Bs[2 * 2 * HALF];  // 64KB
  const int tid = threadIdx.x, wave = tid >> 6, lane = tid & 63;
  const int lm = lane & 15, lg = lane >> 4;

  int bx, by;
  {
    const int gx = gridDim.x;
    if ((gx & 7) == 0) {
      const int id = blockIdx.y * gx + blockIdx.x;
      const int xcd = id & 7, rank = id >> 3;
      const int cw = gx >> 3;
      bx = xcd * cw + rank % cw;
      by = rank / cw;
    } else { bx = blockIdx.x; by = blockIdx.y; }
  }
  const int m0 = by * 256, n0 = bx * 256;
  const int wm = wave >> 2, wn = wave & 3;

  f32x4 acc[8][4];
#pragma unroll
  for (int i = 0; i < 8; ++i)
#pragma unroll
    for (int j = 0; j < 4; ++j) acc[i][j] = (f32x4){0.f, 0.f, 0.f, 0.f};

  const int nt = K >> 6;

  auto stA = [&](int buf, int k0, int h) {
#pragma unroll
    for (int p = 0; p < 2; ++p) {
      int idx = p * 512 + tid;
      int r = idx >> 2, s = idx & 3;
      int sg = s ^ (r & 3) ^ ((r >> 2) & 3);
      async_cp16(A + (size_t)(m0 + r) * K + k0 + h * 32 + sg * 8,
                 As + buf * (2 * HALF) + h * HALF + p * 8192 + wave * 1024);
    }
  };
  auto stB = [&](int buf, int k0, int h) {
#pragma unroll
    for (int p = 0; p < 2; ++p) {
      int idx = p * 512 + tid;
      int r = idx >> 2, s = idx & 3;
      int sg = s ^ (r & 3) ^ ((r >> 2) & 3);
      async_cp16(W + (size_t)(n0 + r) * K + k0 + h * 32 + sg * 8,
                 Bs + buf * (2 * HALF) + h * HALF + p * 8192 + wave * 1024);
    }
  };

  bf16x8 a[4], b[4];
  auto lda = [&](int buf, int mg, int ks) {
#pragma unroll
    for (int i = 0; i < 4; ++i) {
      const int r = wm * 128 + mg * 64 + i * 16 + lm;
      const int sl = lg ^ (r & 3) ^ ((r >> 2) & 3);
      a[i] = *(const bf16x8*)(As + buf * (2 * HALF) + ks * HALF + r * 64 + sl * 16);
    }
  };
  auto ldb = [&](int buf, int ks) {
#pragma unroll
    for (int j = 0; j < 4; ++j) {
      const int r = wn * 64 + j * 16 + lm;
      const int sl = lg ^ (r & 3) ^ ((r >> 2) & 3);
      b[j] = *(const bf16x8*)(Bs + buf * (2 * HALF) + ks * HALF + r * 64 + sl * 16);
    }
  };

#define SB __builtin_amdgcn_sched_barrier(0)
#define LGKM0() do { asm volatile("s_waitcnt lgkmcnt(0)" ::: "memory"); SB; } while (0)
#define MM(MB)                                                          \
  do {                                                                  \
    __builtin_amdgcn_s_setprio(1);                                      \
    _Pragma("unroll")                                                   \
    for (int i = 0; i < 4; ++i)                                         \
      _Pragma("unroll")                                                 \
      for (int j = 0; j < 4; ++j)                                       \
        acc[(MB) + i][j] = __builtin_amdgcn_mfma_f32_16x16x32_bf16(     \
            a[i], b[j], acc[(MB) + i][j], 0, 0, 0);                     \
    __builtin_amdgcn_s_setprio(0);                                      \
    SB;                                                                 \
  } while (0)

  // prologue: tile 0 fully staged, drain once, sync
  stA(0, 0, 0); stB(0, 0, 0); stA(0, 0, 1); stB(0, 0, 1);
  asm volatile("s_waitcnt vmcnt(0)" ::: "memory");
  SB;
  barrier_nofence();

  for (int t = 0; t < nt; ++t) {
    const int cur = t & 1, nb = cur ^ 1;
    const bool pf = (t + 1 < nt);
    const int nk = (t + 1) << 6;

    // ---- P0: (mg0, ks0) ; stage A-h0(t+1)
    lda(cur, 0, 0); ldb(cur, 0);
    if (pf) stA(nb, nk, 0);
    SB;
    barrier_nofence();
    LGKM0();
    MM(0);
    barrier_nofence();

    // ---- P1: (mg1, ks0) ; stage B-h0(t+1)
    lda(cur, 1, 0);
    if (pf) stB(nb, nk, 0);
    SB;
    barrier_nofence();
    LGKM0();
    MM(4);
    if (pf) asm volatile("s_waitcnt vmcnt(4)" ::: "memory");
    else    asm volatile("s_waitcnt vmcnt(0)" ::: "memory");
    SB;
    barrier_nofence();

    // ---- P2: (mg1, ks1) ; stage A-h1(t+1)
    lda(cur, 1, 1); ldb(cur, 1);
    if (pf) stA(nb, nk, 1);
    SB;
    barrier_nofence();
    LGKM0();
    MM(4);
    barrier_nofence();

    // ---- P3: (mg0, ks1) ; stage B-h1(t+1)
    lda(cur, 0, 1);
    if (pf) stB(nb, nk, 1);
    SB;
    barrier_nofence();
    LGKM0();
    MM(0);
    if (pf) { asm volatile("s_waitcnt vmcnt(4)" ::: "memory"); SB; }
    barrier_nofence();
  }
#undef MM
#undef LGKM0
#undef SB

  // epilogue: C/D layout col=lane&15, row=(lane>>4)*4+reg ; bf16 store
#pragma unroll
  for (int i = 0; i < 8; ++i) {
    const int row_b = m0 + wm * 128 + i * 16 + lg * 4;
#pragma unroll
    for (int j = 0; j < 4; ++j) {
      const int col = n0 + wn * 64 + j * 16 + lm;
#pragma unroll
      for (int r = 0; r < 4; ++r) {
        size_t idx = (size_t)(row_b + r) * N + col;
        Out[idx] = f2bf(acc[i][j][r]);
      }
    }
  }
}

// ---------------- Flash attention v5: QBLK=128, 8 waves, staged K+V, PAIRED q-tiles ----------------
__global__ __launch_bounds__(512) void attn_kernel(const u16* __restrict__ q,
                                                   const u16* __restrict__ kg,
                                                   const u16* __restrict__ vt,
                                                   u16* __restrict__ out) {
  __shared__ __align__(16) u16 Klds[64 * 128];
  __shared__ __align__(16) u16 Vlds[128 * 64];
  __shared__ __align__(16) u16 Plds[8][16 * 72];
  const int tid = threadIdx.x, wave = tid >> 6, lane = tid & 63;
  const int bh = blockIdx.y, b = bh >> 4, h = bh & 15;
  const float slope = exp2f(-0.5f * (float)(h + 1));
  const int lm = lane & 15, lg = lane >> 4;
  const int crow = lg * 4;
  const int NT = NS / 128;
  u16* pw = Plds[wave];

#pragma unroll 1
  for (int half = 0; half < 2; ++half) {
    const int qt = half == 0 ? (NT - 1 - (int)blockIdx.x) : (int)blockIdx.x;
    const int q0 = qt * 128;

    bf16x8 qf[4];
    {
      const int qrow = q0 + wave * 16 + lm;
      const u16* qbase = q + ((size_t)bh * NS + qrow) * NHD + lg * 8;
#pragma unroll
      for (int kc = 0; kc < 4; ++kc) qf[kc] = *(const bf16x8*)(qbase + kc * 32);
    }

    float Mr[4], Lr[4];
    f32x4 O[8];
#pragma unroll
    for (int r = 0; r < 4; ++r) { Mr[r] = -__builtin_inff(); Lr[r] = 0.f; }
#pragma unroll
    for (int t = 0; t < 8; ++t) O[t] = (f32x4){0.f, 0.f, 0.f, 0.f};

    const int ntiles = 2 * qt + 2;
    for (int t0 = 0; t0 < ntiles; ++t0) {
      const int kv0 = t0 * 64;
      __syncthreads();
#pragma unroll
      for (int p = 0; p < 2; ++p) {
        int X = p * 8192 + tid * 16;
        int kv = X >> 8;
        int sl = (X >> 4) & 15;
        const u16* src = kg + ((size_t)b * NS + kv0 + kv) * NHD + ((sl ^ (kv & 7)) * 8);
        async_cp16(src, (char*)Klds + p * 8192 + wave * 1024);
      }
#pragma unroll
      for (int p = 0; p < 2; ++p) {
        int X = p * 8192 + tid * 16;
        int d = X >> 7;
        int sl = (X >> 4) & 7;
        const u16* src = vt + ((size_t)b * 128 + d) * NS + kv0 + ((sl ^ (d & 7)) * 8);
        async_cp16(src, (char*)Vlds + p * 8192 + wave * 1024);
      }
      __syncthreads();

      f32x4 sc[4];
#pragma unroll
      for (int sub = 0; sub < 4; ++sub) sc[sub] = (f32x4){0.f, 0.f, 0.f, 0.f};
#pragma unroll
      for (int sub = 0; sub < 4; ++sub) {
        const int kv = sub * 16 + lm;
#pragma unroll
        for (int kc = 0; kc < 4; ++kc) {
          const int slot = (kc * 4 + lg) ^ (kv & 7);
          bf16x8 kf = *(const bf16x8*)((const char*)Klds + kv * 256 + slot * 16);
          sc[sub] = __builtin_amdgcn_mfma_f32_16x16x32_bf16(qf[kc], kf, sc[sub], 0, 0, 0);
        }
      }

      float esc[4], pp[4][4];
#pragma unroll
      for (int r = 0; r < 4; ++r) {
        const int sq = q0 + wave * 16 + crow + r;
        float v[4];
#pragma unroll
        for (int sub = 0; sub < 4; ++sub) {
          const int kc_ = kv0 + sub * 16 + lm;
          v[sub] = (kc_ <= sq) ? sc[sub][r] - slope * (float)(sq - kc_) : -1e9f;
        }
        float mx = fmaxf(fmaxf(v[0], v[1]), fmaxf(v[2], v[3]));
        mx = fmaxf(mx, __shfl_xor(mx, 1));
        mx = fmaxf(mx, __shfl_xor(mx, 2));
        mx = fmaxf(mx, __shfl_xor(mx, 4));
        mx = fmaxf(mx, __shfl_xor(mx, 8));
        const float newM = fmaxf(Mr[r], mx);
        esc[r] = __expf(Mr[r] - newM);
        float rs = 0.f;
#pragma unroll
        for (int sub = 0; sub < 4; ++sub) { pp[sub][r] = __expf(v[sub] - newM); rs += pp[sub][r]; }
        rs += __shfl_xor(rs, 1);
        rs += __shfl_xor(rs, 2);
        rs += __shfl_xor(rs, 4);
        rs += __shfl_xor(rs, 8);
        Lr[r] = Lr[r] * esc[r] + rs;
        Mr[r] = newM;
      }
#pragma unroll
      for (int t = 0; t < 8; ++t) {
        O[t][0] *= esc[0]; O[t][1] *= esc[1]; O[t][2] *= esc[2]; O[t][3] *= esc[3];
      }

#pragma unroll
      for (int sub = 0; sub < 4; ++sub)
#pragma unroll
        for (int r = 0; r < 4; ++r)
          pw[(crow + r) * 72 + sub * 16 + lm] = f2bf(pp[sub][r]);

      bf16x8 pa0 = *(const bf16x8*)&pw[lm * 72 + lg * 8];
      bf16x8 pa1 = *(const bf16x8*)&pw[lm * 72 + 32 + lg * 8];

#pragma unroll
      for (int dt = 0; dt < 8; ++dt) {
        const int d = dt * 16 + lm;
        const int s0 = (lg) ^ (d & 7);
        const int s1 = (4 + lg) ^ (d & 7);
        bf16x8 vf0 = *(const bf16x8*)((const char*)Vlds + d * 128 + s0 * 16);
        bf16x8 vf1 = *(const bf16x8*)((const char*)Vlds + d * 128 + s1 * 16);
        O[dt] = __builtin_amdgcn_mfma_f32_16x16x32_bf16(pa0, vf0, O[dt], 0, 0, 0);
        O[dt] = __builtin_amdgcn_mfma_f32_16x16x32_bf16(pa1, vf1, O[dt], 0, 0, 0);
      }
    }

#pragma unroll
    for (int dt = 0; dt < 8; ++dt) {
#pragma unroll
      for (int r = 0; r < 4; ++r) {
        const int sq = q0 + wave * 16 + crow + r;
        out[((size_t)b * NS + sq) * ND + h * NHD + dt * 16 + lm] = f2bf(O[dt][r] / Lr[r]);
      }
    }
  }
}

// ---------------- host ----------------
extern "C" void kernel_launch(void* const* d_in, const int* in_sizes, int n_in,
                              void* d_out, int out_size, void* d_ws, size_t ws_size,
                              hipStream_t stream) {
  const float* x   = (const float*)d_in[0];
  const float* wn1 = (const float*)d_in[2];
  const float* wn2 = (const float*)d_in[3];
  const float* qw  = (const float*)d_in[4];
  const float* kvw = (const float*)d_in[5];
  const float* ow  = (const float*)d_in[6];
  const float* w1  = (const float*)d_in[7];
  const float* w2  = (const float*)d_in[8];
  const float* w3  = (const float*)d_in[9];
  float* out = (float*)d_out;

  const size_t MiB = 1024 * 1024;
  const size_t NEED = 161 * MiB;
  if (ws_size < NEED) return;

  char* ws = (char*)d_ws;
  u16*   WQKV   = (u16*)(ws);                 // [0,9.2)
  u16*   AO     = (u16*)(ws + 16 * MiB);      // [16,32)
  u16*   OWB    = (u16*)(ws + 32 * MiB);      // [32,40)
  u16*   W1B    = (u16*)(ws);                 // [0,32)  (after QKV gemm)
  u16*   W2B    = (u16*)(ws + 32 * MiB);      // [32,64) (after O-proj)
  u16*   W3B    = (u16*)(ws);                 // [0,32)  (after W1 gemm)
  u16*   QKVRAW = (u16*)(ws + 64 * MiB);      // [64,83)
  u16*   A1     = (u16*)(ws + 64 * MiB);      // [64,128)
  u16*   KB     = (u16*)(ws + 83 * MiB);      // [83,84)
  u16*   VT     = (u16*)(ws + 84 * MiB);      // [84,85)
  u16*   QB     = (u16*)(ws + 112 * MiB);     // [112,128)
  u16*   X2B    = (u16*)(ws + 128 * MiB);     // [128,144) bf16 residual
  u16*   Hbf    = (u16*)(ws + 144 * MiB);     // [144,160)
  float* COS    = (float*)(ws + 160 * MiB);
  float* SIN    = (float*)(ws + 160 * MiB + 512 * 1024);

  rope_table_kernel<<<(NS * 64 + 255) / 256, 256, 0, stream>>>(COS, SIN);

  // batch cvt #1: qw, kvw, ow  (one dispatch; all destinations live until consumed)
  {
    int n0 = ND * ND / 4, n1 = 256 * ND / 4, n2 = ND * ND / 4;
    int tot = n0 + n1 + n2;
    cvt3_bf16_kernel<<<(tot + 255) / 256, 256, 0, stream>>>(
        qw, WQKV, n0, kvw, WQKV + (size_t)ND * ND, n1, ow, OWB, n2);
  }

  // h = rmsnorm(x, wn1)
  rmsnorm_kernel<0><<<NBS, 256, 0, stream>>>(x, wn1, Hbf);

  // qkv_raw = h @ [qw; kvw]^T   (fused, N=2304; SWAP grid so gridDim.x=32 -> XCD remap)
  gemm3_kernel<0, 1><<<dim3(NBS / 128, NQKV / 128), 256, 0, stream>>>(
      Hbf, WQKV, (void*)QKVRAW, nullptr, NBS, NQKV, ND);

  // rope
  rope_q_kernel<<<(NB * NS * NH * 64) / 256, 256, 0, stream>>>(QKVRAW, COS, SIN, QB);
  rope_kv_kernel<<<(NB * NS * 64) / 256, 256, 0, stream>>>(QKVRAW, COS, SIN, KB, VT);

  // attention -> AO   (QBLK=128, 8 waves, paired q-tiles)
  attn_kernel<<<dim3(NS / 256, NB * NH), 512, 0, stream>>>(QB, KB, VT, AO);

  // x2 = x + ao @ ow^T   (bf16 residual out)
  gemm3_kernel<3><<<dim3(ND / 128, NBS / 128), 256, 0, stream>>>(
      AO, OWB, (void*)X2B, (const void*)x, NBS, ND, ND);

  // h2 = rmsnorm(x2, wn2)
  rmsnorm_kernel<1><<<NBS, 256, 0, stream>>>(X2B, wn2, Hbf);

  // batch cvt #2: w1, w2  (one dispatch; W1B/W2B regions free after O-proj)
  {
    int n0 = NFF * ND / 4, n1 = NFF * ND / 4;
    int tot = n0 + n1;
    cvt3_bf16_kernel<<<(tot + 255) / 256, 256, 0, stream>>>(
        w1, W1B, n0, w2, W2B, n1, nullptr, nullptr, 0);
  }

  // a1 = h2 @ w1^T   (8-phase — the configuration its win was measured in)
  gemm8p_kernel<<<dim3(NFF / 256, NBS / 256), 512, 0, stream>>>(
      Hbf, W1B, A1, NBS, NFF, ND);
  // g = silu(a1) * (h2 @ w2^T)  (gemm3, in-place over A1)
  gemm3_kernel<2><<<dim3(NFF / 128, NBS / 128), 256, 0, stream>>>(
      Hbf, W2B, (void*)A1, (const void*)A1, NBS, NFF, ND);

  // cvt w3 (W3B overwrites W1B, dead after W1 gemm)
  {
    int n0 = ND * NFF / 4;
    cvt3_bf16_kernel<<<(n0 + 255) / 256, 256, 0, stream>>>(
        w3, W3B, n0, nullptr, nullptr, 0, nullptr, nullptr, 0);
  }

  // out = x2 + g @ w3^T   (gemm3)
  gemm3_kernel<4><<<dim3(ND / 128, NBS / 128), 256, 0, stream>>>(
      A1, W3B, (void*)out, (const void*)X2B, NBS, ND, NFF);
}

// Round 22
// 742.681 us; speedup vs baseline: 1.1037x; 1.0511x over previous
//
#include <hip/hip_runtime.h>
#include <stdint.h>

#define NB 2
#define NS 2048
#define ND 2048
#define NH 16
#define NHD 128
#define NFF 8192
#define NBS (NB*NS)   // 4096 rows
#define NQKV 2304     // 2048 q + 256 kv

typedef unsigned short u16;
typedef __attribute__((ext_vector_type(8))) short bf16x8;   // 8 bf16 = 4 VGPRs
typedef __attribute__((ext_vector_type(4))) unsigned short u16x4;
typedef __attribute__((ext_vector_type(4))) float f32x4;

__device__ __forceinline__ u16 f2bf(float f) {
  union { float f; unsigned u; } v; v.f = f;
  unsigned r = v.u + 0x7fffu + ((v.u >> 16) & 1u);   // RNE
  return (u16)(r >> 16);
}
__device__ __forceinline__ float bf2f(u16 h) {
  union { unsigned u; float f; } v; v.u = ((unsigned)h) << 16;
  return v.f;
}
__device__ __forceinline__ void async_cp16(const void* g, void* l) {
  __builtin_amdgcn_global_load_lds((const __attribute__((address_space(1))) void*)g,
                                   (__attribute__((address_space(3))) void*)l, 16, 0, 0);
}
__device__ __forceinline__ void barrier_nofence() {
  asm volatile("" ::: "memory");
  __builtin_amdgcn_s_barrier();
  asm volatile("" ::: "memory");
}

// ---------------- fp32 -> bf16, up to 3 segments in one dispatch ----------------
__global__ void cvt3_bf16_kernel(const float* __restrict__ s0, u16* __restrict__ d0, int n0,
                                 const float* __restrict__ s1, u16* __restrict__ d1, int n1,
                                 const float* __restrict__ s2, u16* __restrict__ d2, int n2) {
  int i = blockIdx.x * blockDim.x + threadIdx.x;   // float4 index
  const float* src; u16* dst; int k;
  if (i < n0)                { src = s0; dst = d0; k = i; }
  else if (i < n0 + n1)      { src = s1; dst = d1; k = i - n0; }
  else if (i < n0 + n1 + n2) { src = s2; dst = d2; k = i - n0 - n1; }
  else return;
  float4 v = reinterpret_cast<const float4*>(src)[k];
  u16x4 o; o.x = f2bf(v.x); o.y = f2bf(v.y); o.z = f2bf(v.z); o.w = f2bf(v.w);
  reinterpret_cast<u16x4*>(dst)[k] = o;
}

// ---------------- RMSNorm, one block per row. BF16IN: 0=fp32 input, 1=bf16 input ----------------
template <int BF16IN>
__global__ __launch_bounds__(256) void rmsnorm_kernel(const void* __restrict__ xin,
                                                      const float* __restrict__ w,
                                                      u16* __restrict__ out) {
  const int row = blockIdx.x, tid = threadIdx.x;
  float vs[8];
  if constexpr (BF16IN == 0) {
    const float* xr = (const float*)xin + (size_t)row * ND;
    float4 a = *reinterpret_cast<const float4*>(xr + tid * 8);
    float4 b = *reinterpret_cast<const float4*>(xr + tid * 8 + 4);
    vs[0]=a.x; vs[1]=a.y; vs[2]=a.z; vs[3]=a.w; vs[4]=b.x; vs[5]=b.y; vs[6]=b.z; vs[7]=b.w;
  } else {
    const u16* xr = (const u16*)xin + (size_t)row * ND;
    bf16x8 v = *reinterpret_cast<const bf16x8*>(xr + tid * 8);
#pragma unroll
    for (int j = 0; j < 8; ++j) vs[j] = bf2f((u16)v[j]);
  }
  float ss = 0.f;
#pragma unroll
  for (int j = 0; j < 8; ++j) ss += vs[j] * vs[j];
#pragma unroll
  for (int off = 32; off > 0; off >>= 1) ss += __shfl_down(ss, off);
  __shared__ float red[4];
  __shared__ float rinv_s;
  if ((tid & 63) == 0) red[tid >> 6] = ss;
  __syncthreads();
  if (tid == 0) rinv_s = rsqrtf((red[0] + red[1] + red[2] + red[3]) * (1.0f / ND) + 1e-6f);
  __syncthreads();
  const float rinv = rinv_s;
  const float* wr = w + tid * 8;
  u16* orow = out + (size_t)row * ND + tid * 8;
#pragma unroll
  for (int j = 0; j < 8; ++j) orow[j] = f2bf(vs[j] * rinv * wr[j]);
}

// ---------------- RoPE cos/sin table [S][64] ----------------
__global__ void rope_table_kernel(float* __restrict__ cosT, float* __restrict__ sinT) {
  int i = blockIdx.x * blockDim.x + threadIdx.x;
  if (i >= NS * 64) return;
  int s = i >> 6, d = i & 63;
  float freq = expf(-(float)d * (9.210340371976184f / 64.0f));  // 10000^(-d/64)
  float ang = (float)s * freq;
  cosT[i] = cosf(ang);
  sinT[i] = sinf(ang);
}

// ---- RoPE for Q: qkvraw [B,S,2304] bf16 -> [B*H, S, HD] bf16, pre-scaled 1/sqrt(HD) ----
__global__ void rope_q_kernel(const u16* __restrict__ qkvraw, const float* __restrict__ cosT,
                              const float* __restrict__ sinT, u16* __restrict__ qout) {
  int i = blockIdx.x * blockDim.x + threadIdx.x;
  if (i >= NB * NS * NH * 64) return;
  int d = i & 63, h = (i >> 6) & 15, s = (i >> 10) & (NS - 1), b = i >> 21;
  size_t rrow = ((size_t)(b * NS + s)) * NQKV + h * NHD;
  float t1 = bf2f(qkvraw[rrow + d]);
  float t2 = bf2f(qkvraw[rrow + d + 64]);
  float c = cosT[(s << 6) + d], sn = sinT[(s << 6) + d];
  const float scale = 0.08838834764831845f;  // 1/sqrt(128)
  size_t orow = (((size_t)(b * NH + h)) * NS + s) * NHD;
  qout[orow + d]      = f2bf((t1 * c - t2 * sn) * scale);
  qout[orow + d + 64] = f2bf((t2 * c + t1 * sn) * scale);
}

// ---- RoPE for K + transpose-copy V: qkvraw[...,2048+] -> k [B,S,HD], vt [B,128,S] ----
__global__ void rope_kv_kernel(const u16* __restrict__ qkvraw, const float* __restrict__ cosT,
                               const float* __restrict__ sinT, u16* __restrict__ kout,
                               u16* __restrict__ vtout) {
  int i = blockIdx.x * blockDim.x + threadIdx.x;
  if (i >= NB * NS * 64) return;
  int d = i & 63, s = (i >> 6) & (NS - 1), b = i >> 17;
  size_t rrow = ((size_t)(b * NS + s)) * NQKV + ND;
  float t1 = bf2f(qkvraw[rrow + d]);
  float t2 = bf2f(qkvraw[rrow + d + 64]);
  float c = cosT[(s << 6) + d], sn = sinT[(s << 6) + d];
  size_t orow = ((size_t)(b * NS + s)) * NHD;
  kout[orow + d]      = f2bf(t1 * c - t2 * sn);
  kout[orow + d + 64] = f2bf(t2 * c + t1 * sn);
  vtout[((size_t)(b * 128 + d)) * NS + s]      = qkvraw[rrow + 128 + d];
  vtout[((size_t)(b * 128 + d + 64)) * NS + s] = qkvraw[rrow + 128 + d + 64];
}

// ---------------- GEMM v9 (m97-structure + swizzle): C = A[M,K] @ W[N,K]^T (bf16) ----------------
// EPI: 0 = bf16 store; 2 = bf16 store silu(Aux_bf16)*acc (in-place ok);
//      3 = bf16 store of (acc + fp32 Aux); 4 = fp32 store of (acc + bf16 Aux)
// SWAP: 1 = gridDim.x indexes M (XCD remap when N-tiles % 8 != 0, e.g. QKV N=2304)
template <int EPI, int SWAP = 0>
__global__ __launch_bounds__(256) void gemm3_kernel(const u16* __restrict__ A,
                                                    const u16* __restrict__ W,
                                                    void* Out, const void* Aux,
                                                    int M, int N, int K) {
  __shared__ __align__(16) char As[128 * 128];
  __shared__ __align__(16) char Bs[128 * 128];
  const int tid = threadIdx.x, wave = tid >> 6, lane = tid & 63;
  const int lm = lane & 15, lg = lane >> 4;

  int bx, by;
  {
    const int gx = gridDim.x;
    if ((gx & 7) == 0) {
      const int id = blockIdx.y * gx + blockIdx.x;
      const int xcd = id & 7, rank = id >> 3;
      const int cw = gx >> 3;
      bx = xcd * cw + rank % cw;
      by = rank / cw;
    } else { bx = blockIdx.x; by = blockIdx.y; }
  }
  const int m0 = (SWAP ? bx : by) * 128, n0 = (SWAP ? by : bx) * 128;
  const int wr = wave >> 1, wc = wave & 1;

  f32x4 acc[4][4];
#pragma unroll
  for (int i = 0; i < 4; ++i)
#pragma unroll
    for (int j = 0; j < 4; ++j) acc[i][j] = (f32x4){0.f, 0.f, 0.f, 0.f};

  for (int k0 = 0; k0 < K; k0 += 64) {
#pragma unroll
    for (int p = 0; p < 4; ++p) {
      int X = p * 4096 + tid * 16;
      int r = X >> 7;
      int sw = ((X >> 4) ^ (X >> 7)) & 7;
      async_cp16(A + (size_t)(m0 + r) * K + k0 + sw * 8, As + p * 4096 + wave * 1024);
      async_cp16(W + (size_t)(n0 + r) * K + k0 + sw * 8, Bs + p * 4096 + wave * 1024);
    }
    __syncthreads();
#pragma unroll
    for (int ks = 0; ks < 2; ++ks) {
      bf16x8 a[4], b[4];
#pragma unroll
      for (int i = 0; i < 4; ++i) {
        const int ra = wr * 64 + i * 16 + lm;
        const int sa = (ks * 4 + lg) ^ (ra & 7);
        a[i] = *(const bf16x8*)(As + ra * 128 + sa * 16);
        const int rb = wc * 64 + i * 16 + lm;
        const int sb = (ks * 4 + lg) ^ (rb & 7);
        b[i] = *(const bf16x8*)(Bs + rb * 128 + sb * 16);
      }
#pragma unroll
      for (int i = 0; i < 4; ++i)
#pragma unroll
        for (int j = 0; j < 4; ++j)
          acc[i][j] = __builtin_amdgcn_mfma_f32_16x16x32_bf16(a[i], b[j], acc[i][j], 0, 0, 0);
    }
    __syncthreads();
  }

#pragma unroll
  for (int i = 0; i < 4; ++i) {
    const int row_b = m0 + wr * 64 + i * 16 + lg * 4;
#pragma unroll
    for (int j = 0; j < 4; ++j) {
      const int col = n0 + wc * 64 + j * 16 + lm;
#pragma unroll
      for (int r = 0; r < 4; ++r) {
        size_t idx = (size_t)(row_b + r) * N + col;
        float v = acc[i][j][r];
        if constexpr (EPI == 0) {
          ((u16*)Out)[idx] = f2bf(v);
        } else if constexpr (EPI == 2) {
          float a1 = bf2f(((const u16*)Aux)[idx]);
          float s = a1 / (1.0f + expf(-a1));   // silu
          ((u16*)Out)[idx] = f2bf(s * v);
        } else if constexpr (EPI == 3) {
          ((u16*)Out)[idx] = f2bf(v + ((const float*)Aux)[idx]);
        } else {
          ((float*)Out)[idx] = v + bf2f(((const u16*)Aux)[idx]);
        }
      }
    }
  }
}

// ---------------- GEMM 8-phase (K-split halves, counted vmcnt): C = A @ W^T bf16 ----------------
// 256x256 tile, BK=64, 8 waves (2M x 4N), 512 threads, LDS 128KB.
// EPI: 0 = bf16 store (W1); 2 = bf16 silu(Aux)*acc in-place (W2 — same geometry as W1).
template <int EPI>
__global__ __launch_bounds__(512, 2) void gemm8p_kernel(const u16* __restrict__ A,
                                                        const u16* __restrict__ W,
                                                        u16* __restrict__ Out,
                                                        const u16* __restrict__ Aux,
                                                        int M, int N, int K) {
  constexpr int HALF = 256 * 64;                 // bytes per K-half (256 rows x 64B)
  __shared__ __align__(16) char As[2 * 2 * HALF];  // [buf][half] 64KB
  __shared__ __align__(16) char Bs[2 * 2 * HALF];  // 64KB
  const int tid = threadIdx.x, wave = tid >> 6, lane = tid & 63;
  const int lm = lane & 15, lg = lane >> 4;

  int bx, by;
  {
    const int gx = gridDim.x;
    if ((gx & 7) == 0) {
      const int id = blockIdx.y * gx + blockIdx.x;
      const int xcd = id & 7, rank = id >> 3;
      const int cw = gx >> 3;
      bx = xcd * cw + rank % cw;
      by = rank / cw;
    } else { bx = blockIdx.x; by = blockIdx.y; }
  }
  const int m0 = by * 256, n0 = bx * 256;
  const int wm = wave >> 2, wn = wave & 3;

  f32x4 acc[8][4];
#pragma unroll
  for (int i = 0; i < 8; ++i)
#pragma unroll
    for (int j = 0; j < 4; ++j) acc[i][j] = (f32x4){0.f, 0.f, 0.f, 0.f};

  const int nt = K >> 6;

  auto stA = [&](int buf, int k0, int h) {
#pragma unroll
    for (int p = 0; p < 2; ++p) {
      int idx = p * 512 + tid;
      int r = idx >> 2, s = idx & 3;
      int sg = s ^ (r & 3) ^ ((r >> 2) & 3);
      async_cp16(A + (size_t)(m0 + r) * K + k0 + h * 32 + sg * 8,
                 As + buf * (2 * HALF) + h * HALF + p * 8192 + wave * 1024);
    }
  };
  auto stB = [&](int buf, int k0, int h) {
#pragma unroll
    for (int p = 0; p < 2; ++p) {
      int idx = p * 512 + tid;
      int r = idx >> 2, s = idx & 3;
      int sg = s ^ (r & 3) ^ ((r >> 2) & 3);
      async_cp16(W + (size_t)(n0 + r) * K + k0 + h * 32 + sg * 8,
                 Bs + buf * (2 * HALF) + h * HALF + p * 8192 + wave * 1024);
    }
  };

  bf16x8 a[4], b[4];
  auto lda = [&](int buf, int mg, int ks) {
#pragma unroll
    for (int i = 0; i < 4; ++i) {
      const int r = wm * 128 + mg * 64 + i * 16 + lm;
      const int sl = lg ^ (r & 3) ^ ((r >> 2) & 3);
      a[i] = *(const bf16x8*)(As + buf * (2 * HALF) + ks * HALF + r * 64 + sl * 16);
    }
  };
  auto ldb = [&](int buf, int ks) {
#pragma unroll
    for (int j = 0; j < 4; ++j) {
      const int r = wn * 64 + j * 16 + lm;
      const int sl = lg ^ (r & 3) ^ ((r >> 2) & 3);
      b[j] = *(const bf16x8*)(Bs + buf * (2 * HALF) + ks * HALF + r * 64 + sl * 16);
    }
  };

#define SB __builtin_amdgcn_sched_barrier(0)
#define LGKM0() do { asm volatile("s_waitcnt lgkmcnt(0)" ::: "memory"); SB; } while (0)
#define MM(MB)                                                          \
  do {                                                                  \
    __builtin_amdgcn_s_setprio(1);                                      \
    _Pragma("unroll")                                                   \
    for (int i = 0; i < 4; ++i)                                         \
      _Pragma("unroll")                                                 \
      for (int j = 0; j < 4; ++j)                                       \
        acc[(MB) + i][j] = __builtin_amdgcn_mfma_f32_16x16x32_bf16(     \
            a[i], b[j], acc[(MB) + i][j], 0, 0, 0);                     \
    __builtin_amdgcn_s_setprio(0);                                      \
    SB;                                                                 \
  } while (0)

  // prologue: tile 0 fully staged, drain once, sync
  stA(0, 0, 0); stB(0, 0, 0); stA(0, 0, 1); stB(0, 0, 1);
  asm volatile("s_waitcnt vmcnt(0)" ::: "memory");
  SB;
  barrier_nofence();

  for (int t = 0; t < nt; ++t) {
    const int cur = t & 1, nb = cur ^ 1;
    const bool pf = (t + 1 < nt);
    const int nk = (t + 1) << 6;

    // ---- P0: (mg0, ks0) ; stage A-h0(t+1)
    lda(cur, 0, 0); ldb(cur, 0);
    if (pf) stA(nb, nk, 0);
    SB;
    barrier_nofence();
    LGKM0();
    MM(0);
    barrier_nofence();

    // ---- P1: (mg1, ks0) ; stage B-h0(t+1)
    lda(cur, 1, 0);
    if (pf) stB(nb, nk, 0);
    SB;
    barrier_nofence();
    LGKM0();
    MM(4);
    if (pf) asm volatile("s_waitcnt vmcnt(4)" ::: "memory");
    else    asm volatile("s_waitcnt vmcnt(0)" ::: "memory");
    SB;
    barrier_nofence();

    // ---- P2: (mg1, ks1) ; stage A-h1(t+1)
    lda(cur, 1, 1); ldb(cur, 1);
    if (pf) stA(nb, nk, 1);
    SB;
    barrier_nofence();
    LGKM0();
    MM(4);
    barrier_nofence();

    // ---- P3: (mg0, ks1) ; stage B-h1(t+1)
    lda(cur, 0, 1);
    if (pf) stB(nb, nk, 1);
    SB;
    barrier_nofence();
    LGKM0();
    MM(0);
    if (pf) { asm volatile("s_waitcnt vmcnt(4)" ::: "memory"); SB; }
    barrier_nofence();
  }
#undef MM
#undef LGKM0
#undef SB

  // epilogue: C/D layout col=lane&15, row=(lane>>4)*4+reg
#pragma unroll
  for (int i = 0; i < 8; ++i) {
    const int row_b = m0 + wm * 128 + i * 16 + lg * 4;
#pragma unroll
    for (int j = 0; j < 4; ++j) {
      const int col = n0 + wn * 64 + j * 16 + lm;
#pragma unroll
      for (int r = 0; r < 4; ++r) {
        size_t idx = (size_t)(row_b + r) * N + col;
        float v = acc[i][j][r];
        if constexpr (EPI == 0) {
          Out[idx] = f2bf(v);
        } else {
          float a1 = bf2f(Aux[idx]);
          float s = a1 / (1.0f + expf(-a1));   // silu
          Out[idx] = f2bf(s * v);
        }
      }
    }
  }
}

// ---------------- Flash attention v5: QBLK=128, 8 waves, staged K+V, PAIRED q-tiles ----------------
__global__ __launch_bounds__(512) void attn_kernel(const u16* __restrict__ q,
                                                   const u16* __restrict__ kg,
                                                   const u16* __restrict__ vt,
                                                   u16* __restrict__ out) {
  __shared__ __align__(16) u16 Klds[64 * 128];
  __shared__ __align__(16) u16 Vlds[128 * 64];
  __shared__ __align__(16) u16 Plds[8][16 * 72];
  const int tid = threadIdx.x, wave = tid >> 6, lane = tid & 63;
  const int bh = blockIdx.y, b = bh >> 4, h = bh & 15;
  const float slope = exp2f(-0.5f * (float)(h + 1));
  const int lm = lane & 15, lg = lane >> 4;
  const int crow = lg * 4;
  const int NT = NS / 128;
  u16* pw = Plds[wave];

#pragma unroll 1
  for (int half = 0; half < 2; ++half) {
    const int qt = half == 0 ? (NT - 1 - (int)blockIdx.x) : (int)blockIdx.x;
    const int q0 = qt * 128;

    bf16x8 qf[4];
    {
      const int qrow = q0 + wave * 16 + lm;
      const u16* qbase = q + ((size_t)bh * NS + qrow) * NHD + lg * 8;
#pragma unroll
      for (int kc = 0; kc < 4; ++kc) qf[kc] = *(const bf16x8*)(qbase + kc * 32);
    }

    float Mr[4], Lr[4];
    f32x4 O[8];
#pragma unroll
    for (int r = 0; r < 4; ++r) { Mr[r] = -__builtin_inff(); Lr[r] = 0.f; }
#pragma unroll
    for (int t = 0; t < 8; ++t) O[t] = (f32x4){0.f, 0.f, 0.f, 0.f};

    const int ntiles = 2 * qt + 2;
    for (int t0 = 0; t0 < ntiles; ++t0) {
      const int kv0 = t0 * 64;
      __syncthreads();
#pragma unroll
      for (int p = 0; p < 2; ++p) {
        int X = p * 8192 + tid * 16;
        int kv = X >> 8;
        int sl = (X >> 4) & 15;
        const u16* src = kg + ((size_t)b * NS + kv0 + kv) * NHD + ((sl ^ (kv & 7)) * 8);
        async_cp16(src, (char*)Klds + p * 8192 + wave * 1024);
      }
#pragma unroll
      for (int p = 0; p < 2; ++p) {
        int X = p * 8192 + tid * 16;
        int d = X >> 7;
        int sl = (X >> 4) & 7;
        const u16* src = vt + ((size_t)b * 128 + d) * NS + kv0 + ((sl ^ (d & 7)) * 8);
        async_cp16(src, (char*)Vlds + p * 8192 + wave * 1024);
      }
      __syncthreads();

      f32x4 sc[4];
#pragma unroll
      for (int sub = 0; sub < 4; ++sub) sc[sub] = (f32x4){0.f, 0.f, 0.f, 0.f};
      __builtin_amdgcn_s_setprio(1);
#pragma unroll
      for (int sub = 0; sub < 4; ++sub) {
        const int kv = sub * 16 + lm;
#pragma unroll
        for (int kc = 0; kc < 4; ++kc) {
          const int slot = (kc * 4 + lg) ^ (kv & 7);
          bf16x8 kf = *(const bf16x8*)((const char*)Klds + kv * 256 + slot * 16);
          sc[sub] = __builtin_amdgcn_mfma_f32_16x16x32_bf16(qf[kc], kf, sc[sub], 0, 0, 0);
        }
      }
      __builtin_amdgcn_s_setprio(0);

      float esc[4], pp[4][4];
#pragma unroll
      for (int r = 0; r < 4; ++r) {
        const int sq = q0 + wave * 16 + crow + r;
        float v[4];
#pragma unroll
        for (int sub = 0; sub < 4; ++sub) {
          const int kc_ = kv0 + sub * 16 + lm;
          v[sub] = (kc_ <= sq) ? sc[sub][r] - slope * (float)(sq - kc_) : -1e9f;
        }
        float mx = fmaxf(fmaxf(v[0], v[1]), fmaxf(v[2], v[3]));
        mx = fmaxf(mx, __shfl_xor(mx, 1));
        mx = fmaxf(mx, __shfl_xor(mx, 2));
        mx = fmaxf(mx, __shfl_xor(mx, 4));
        mx = fmaxf(mx, __shfl_xor(mx, 8));
        const float newM = fmaxf(Mr[r], mx);
        esc[r] = __expf(Mr[r] - newM);
        float rs = 0.f;
#pragma unroll
        for (int sub = 0; sub < 4; ++sub) { pp[sub][r] = __expf(v[sub] - newM); rs += pp[sub][r]; }
        rs += __shfl_xor(rs, 1);
        rs += __shfl_xor(rs, 2);
        rs += __shfl_xor(rs, 4);
        rs += __shfl_xor(rs, 8);
        Lr[r] = Lr[r] * esc[r] + rs;
        Mr[r] = newM;
      }
#pragma unroll
      for (int t = 0; t < 8; ++t) {
        O[t][0] *= esc[0]; O[t][1] *= esc[1]; O[t][2] *= esc[2]; O[t][3] *= esc[3];
      }

#pragma unroll
      for (int sub = 0; sub < 4; ++sub)
#pragma unroll
        for (int r = 0; r < 4; ++r)
          pw[(crow + r) * 72 + sub * 16 + lm] = f2bf(pp[sub][r]);

      bf16x8 pa0 = *(const bf16x8*)&pw[lm * 72 + lg * 8];
      bf16x8 pa1 = *(const bf16x8*)&pw[lm * 72 + 32 + lg * 8];

      __builtin_amdgcn_s_setprio(1);
#pragma unroll
      for (int dt = 0; dt < 8; ++dt) {
        const int d = dt * 16 + lm;
        const int s0 = (lg) ^ (d & 7);
        const int s1 = (4 + lg) ^ (d & 7);
        bf16x8 vf0 = *(const bf16x8*)((const char*)Vlds + d * 128 + s0 * 16);
        bf16x8 vf1 = *(const bf16x8*)((const char*)Vlds + d * 128 + s1 * 16);
        O[dt] = __builtin_amdgcn_mfma_f32_16x16x32_bf16(pa0, vf0, O[dt], 0, 0, 0);
        O[dt] = __builtin_amdgcn_mfma_f32_16x16x32_bf16(pa1, vf1, O[dt], 0, 0, 0);
      }
      __builtin_amdgcn_s_setprio(0);
    }

#pragma unroll
    for (int dt = 0; dt < 8; ++dt) {
#pragma unroll
      for (int r = 0; r < 4; ++r) {
        const int sq = q0 + wave * 16 + crow + r;
        out[((size_t)b * NS + sq) * ND + h * NHD + dt * 16 + lm] = f2bf(O[dt][r] / Lr[r]);
      }
    }
  }
}

// ---------------- host ----------------
extern "C" void kernel_launch(void* const* d_in, const int* in_sizes, int n_in,
                              void* d_out, int out_size, void* d_ws, size_t ws_size,
                              hipStream_t stream) {
  const float* x   = (const float*)d_in[0];
  const float* wn1 = (const float*)d_in[2];
  const float* wn2 = (const float*)d_in[3];
  const float* qw  = (const float*)d_in[4];
  const float* kvw = (const float*)d_in[5];
  const float* ow  = (const float*)d_in[6];
  const float* w1  = (const float*)d_in[7];
  const float* w2  = (const float*)d_in[8];
  const float* w3  = (const float*)d_in[9];
  float* out = (float*)d_out;

  const size_t MiB = 1024 * 1024;
  const size_t NEED = 161 * MiB;
  if (ws_size < NEED) return;

  char* ws = (char*)d_ws;
  u16*   WQKV   = (u16*)(ws);                 // [0,9.2)
  u16*   AO     = (u16*)(ws + 16 * MiB);      // [16,32)
  u16*   OWB    = (u16*)(ws + 32 * MiB);      // [32,40)
  u16*   W1B    = (u16*)(ws);                 // [0,32)  (after QKV gemm)
  u16*   W2B    = (u16*)(ws + 32 * MiB);      // [32,64) (after O-proj)
  u16*   W3B    = (u16*)(ws);                 // [0,32)  (after W1 gemm)
  u16*   QKVRAW = (u16*)(ws + 64 * MiB);      // [64,83)
  u16*   A1     = (u16*)(ws + 64 * MiB);      // [64,128)
  u16*   KB     = (u16*)(ws + 83 * MiB);      // [83,84)
  u16*   VT     = (u16*)(ws + 84 * MiB);      // [84,85)
  u16*   QB     = (u16*)(ws + 112 * MiB);     // [112,128)
  u16*   X2B    = (u16*)(ws + 128 * MiB);     // [128,144) bf16 residual
  u16*   Hbf    = (u16*)(ws + 144 * MiB);     // [144,160)
  float* COS    = (float*)(ws + 160 * MiB);
  float* SIN    = (float*)(ws + 160 * MiB + 512 * 1024);

  rope_table_kernel<<<(NS * 64 + 255) / 256, 256, 0, stream>>>(COS, SIN);

  // batch cvt #1: qw, kvw, ow
  {
    int n0 = ND * ND / 4, n1 = 256 * ND / 4, n2 = ND * ND / 4;
    int tot = n0 + n1 + n2;
    cvt3_bf16_kernel<<<(tot + 255) / 256, 256, 0, stream>>>(
        qw, WQKV, n0, kvw, WQKV + (size_t)ND * ND, n1, ow, OWB, n2);
  }

  // h = rmsnorm(x, wn1)
  rmsnorm_kernel<0><<<NBS, 256, 0, stream>>>(x, wn1, Hbf);

  // qkv_raw = h @ [qw; kvw]^T   (fused, N=2304; SWAP grid so gridDim.x=32 -> XCD remap)
  gemm3_kernel<0, 1><<<dim3(NBS / 128, NQKV / 128), 256, 0, stream>>>(
      Hbf, WQKV, (void*)QKVRAW, nullptr, NBS, NQKV, ND);

  // rope
  rope_q_kernel<<<(NB * NS * NH * 64) / 256, 256, 0, stream>>>(QKVRAW, COS, SIN, QB);
  rope_kv_kernel<<<(NB * NS * 64) / 256, 256, 0, stream>>>(QKVRAW, COS, SIN, KB, VT);

  // attention -> AO   (QBLK=128, 8 waves, paired q-tiles, setprio on MFMA clusters)
  attn_kernel<<<dim3(NS / 256, NB * NH), 512, 0, stream>>>(QB, KB, VT, AO);

  // x2 = x + ao @ ow^T   (bf16 residual out)
  gemm3_kernel<3><<<dim3(ND / 128, NBS / 128), 256, 0, stream>>>(
      AO, OWB, (void*)X2B, (const void*)x, NBS, ND, ND);

  // h2 = rmsnorm(x2, wn2)
  rmsnorm_kernel<1><<<NBS, 256, 0, stream>>>(X2B, wn2, Hbf);

  // batch cvt #2: w1, w2
  {
    int n0 = NFF * ND / 4, n1 = NFF * ND / 4;
    int tot = n0 + n1;
    cvt3_bf16_kernel<<<(tot + 255) / 256, 256, 0, stream>>>(
        w1, W1B, n0, w2, W2B, n1, nullptr, nullptr, 0);
  }

  // a1 = h2 @ w1^T   (8-phase, validated geometry)
  gemm8p_kernel<0><<<dim3(NFF / 256, NBS / 256), 512, 0, stream>>>(
      Hbf, W1B, A1, nullptr, NBS, NFF, ND);
  // g = silu(a1) * (h2 @ w2^T)  (8-phase retry: identical geometry, EPI2 in-place)
  gemm8p_kernel<2><<<dim3(NFF / 256, NBS / 256), 512, 0, stream>>>(
      Hbf, W2B, A1, A1, NBS, NFF, ND);

  // cvt w3 (W3B overwrites W1B, dead after W1 gemm)
  {
    int n0 = ND * NFF / 4;
    cvt3_bf16_kernel<<<(n0 + 255) / 256, 256, 0, stream>>>(
        w3, W3B, n0, nullptr, nullptr, 0, nullptr, nullptr, 0);
  }

  // out = x2 + g @ w3^T   (gemm3)
  gemm3_kernel<4><<<dim3(ND / 128, NBS / 128), 256, 0, stream>>>(
      A1, W3B, (void*)out, (const void*)X2B, NBS, ND, NFF);
}